// Round 1
// baseline (3111.761 us; speedup 1.0000x reference)
//
#include <hip/hip_runtime.h>
#include <hip/hip_bf16.h>

#define BB 256
#define NN 512
#define HH 128
#define MM (BB*NN)

// XOR-swizzled index into a 64x64 f32 LDS tile: element (r,c) ->
// r*64 + swizzled column. Keeps 16B quads contiguous & aligned.
__device__ __forceinline__ int swz(int r, int c) {
  return r*64 + ((((c>>2) ^ (r>>2)) & 15) << 2) + (c & 3);
}

// OUT[M,128] = (LNRELU ? relu(LN(X@W + b)) : X@W + b)
// 32 rows per block, 256 threads. Safe for X == OUT (tile staged in LDS).
template<bool LNRELU>
__global__ __launch_bounds__(256) void linear_kernel(
    const float* X, const float* __restrict__ W,
    const float* __restrict__ bias, const float* __restrict__ gamma,
    const float* __restrict__ beta, float* OUT)
{
  __shared__ float ws[HH*HH];   // W[k][c]  64KB
  __shared__ float xs[32*HH];   // x tile / out tile  16KB
  const int t = threadIdx.x;
  const long rowbase = (long)blockIdx.x * 32;

  for (int i = 0; i < HH*HH/256; i++) ws[t + 256*i] = W[t + 256*i];
  const float* xp = X + rowbase*HH;
  for (int i = 0; i < 32*HH/256; i++) xs[t + 256*i] = xp[t + 256*i];
  __syncthreads();

  const int c  = t & 127;     // output column
  const int rh = t >> 7;      // row parity; thread owns rows rh, rh+2, ... (16 rows)
  float acc[16];
  const float bc = bias[c];
  #pragma unroll
  for (int j = 0; j < 16; j++) acc[j] = bc;

  for (int k = 0; k < HH; k += 4) {
    const float w0 = ws[(k+0)*HH + c];
    const float w1 = ws[(k+1)*HH + c];
    const float w2 = ws[(k+2)*HH + c];
    const float w3 = ws[(k+3)*HH + c];
    #pragma unroll
    for (int j = 0; j < 16; j++) {
      const float4 x4 = *(const float4*)&xs[(rh + 2*j)*HH + k];
      acc[j] = fmaf(x4.x, w0, acc[j]);
      acc[j] = fmaf(x4.y, w1, acc[j]);
      acc[j] = fmaf(x4.z, w2, acc[j]);
      acc[j] = fmaf(x4.w, w3, acc[j]);
    }
  }

  if constexpr (!LNRELU) {
    float* op = OUT + rowbase*HH;
    #pragma unroll
    for (int j = 0; j < 16; j++) op[(rh + 2*j)*HH + c] = acc[j];
  } else {
    __syncthreads();                       // xs reads done everywhere
    #pragma unroll
    for (int j = 0; j < 16; j++) xs[(rh + 2*j)*HH + c] = acc[j];
    __syncthreads();
    const int wave = t >> 6, lane = t & 63;
    const float g0 = gamma[lane*2],   g1 = gamma[lane*2+1];
    const float p0 = beta[lane*2],    p1 = beta[lane*2+1];
    for (int r = wave; r < 32; r += 4) {
      const float2 v2 = *(const float2*)&xs[r*HH + lane*2];
      float s  = v2.x + v2.y;
      float ss = v2.x*v2.x + v2.y*v2.y;
      #pragma unroll
      for (int off = 1; off < 64; off <<= 1) {
        s  += __shfl_xor(s,  off);
        ss += __shfl_xor(ss, off);
      }
      const float mean = s * (1.0f/128.0f);
      const float var  = ss * (1.0f/128.0f) - mean*mean;
      const float rstd = rsqrtf(var + 1e-5f);
      float2 o;
      o.x = fmaxf((v2.x - mean)*rstd*g0 + p0, 0.0f);
      o.y = fmaxf((v2.y - mean)*rstd*g1 + p1, 0.0f);
      *(float2*)&OUT[(rowbase + r)*HH + lane*2] = o;
    }
  }
}

// Flash-style fused attention for one (b, head, 64-row q-tile).
// QCTX: used as Q input, then overwritten with CTX for the same region.
__global__ __launch_bounds__(256) void attn_kernel(
    float* QCTX, const float* __restrict__ K, const float* __restrict__ V,
    const int* __restrict__ lengths)
{
  __shared__ float qs[64*64], ks[64*64], vs[64*64], ps[64*64];
  const int t    = threadIdx.x;
  const int bid  = blockIdx.x;
  const int qt   = bid & 7;
  const int head = (bid >> 3) & 1;
  const int b    = bid >> 4;
  const int L    = lengths[b];
  const int q0   = qt * 64;
  const float scale = 0.125f;  // 1/sqrt(64)

  {
    const float* qp = QCTX + ((long)b*NN + q0)*HH + head*64;
    #pragma unroll
    for (int i = 0; i < 16; i++) {
      const int idx = t + 256*i;
      const int r = idx >> 6, cc = idx & 63;
      qs[swz(r, cc)] = qp[r*HH + cc];
    }
  }

  const int rg = t >> 4;   // q-row group: rows 4*rg..4*rg+3
  const int cg = t & 15;   // k-col group: cols 4*cg..4*cg+3 (and ctx dims 4*cg..)
  float m_run[4], l_run[4], ctxa[4][4];
  #pragma unroll
  for (int i = 0; i < 4; i++) {
    m_run[i] = -3.0e38f; l_run[i] = 0.0f;
    #pragma unroll
    for (int j = 0; j < 4; j++) ctxa[i][j] = 0.0f;
  }

  for (int ch = 0; ch < 8; ch++) {
    __syncthreads();   // previous PV reads complete before restaging
    const float* kp = K + ((long)b*NN + ch*64)*HH + head*64;
    const float* vp = V + ((long)b*NN + ch*64)*HH + head*64;
    #pragma unroll
    for (int i = 0; i < 16; i++) {
      const int idx = t + 256*i;
      const int r = idx >> 6, cc = idx & 63;
      ks[swz(r, cc)] = kp[r*HH + cc];
      vs[swz(r, cc)] = vp[r*HH + cc];
    }
    __syncthreads();

    // scores S[4][4] for rows 4rg+i, cols 4cg+j
    float s[4][4];
    #pragma unroll
    for (int i = 0; i < 4; i++)
      #pragma unroll
      for (int j = 0; j < 4; j++) s[i][j] = 0.0f;

    for (int d4 = 0; d4 < 16; d4++) {
      float4 qv[4], kv[4];
      #pragma unroll
      for (int i = 0; i < 4; i++) qv[i] = *(const float4*)&qs[swz(4*rg+i, 4*d4)];
      #pragma unroll
      for (int j = 0; j < 4; j++) kv[j] = *(const float4*)&ks[swz(4*cg+j, 4*d4)];
      #pragma unroll
      for (int i = 0; i < 4; i++)
        #pragma unroll
        for (int j = 0; j < 4; j++) {
          s[i][j] = fmaf(qv[i].x, kv[j].x, s[i][j]);
          s[i][j] = fmaf(qv[i].y, kv[j].y, s[i][j]);
          s[i][j] = fmaf(qv[i].z, kv[j].z, s[i][j]);
          s[i][j] = fmaf(qv[i].w, kv[j].w, s[i][j]);
        }
    }

    // scale + mask bias + online softmax (16-lane row groups)
    #pragma unroll
    for (int i = 0; i < 4; i++) {
      const bool qvalid = (q0 + 4*rg + i) < L;
      float cm = -3.0e38f;
      #pragma unroll
      for (int j = 0; j < 4; j++) {
        const bool kvalid = (ch*64 + 4*cg + j) < L;
        s[i][j] = s[i][j]*scale + ((qvalid && kvalid) ? 0.0f : -10000.0f);
        cm = fmaxf(cm, s[i][j]);
      }
      #pragma unroll
      for (int off = 1; off < 16; off <<= 1) cm = fmaxf(cm, __shfl_xor(cm, off));
      const float newm = fmaxf(m_run[i], cm);
      const float corr = __expf(m_run[i] - newm);
      float rs = 0.0f;
      #pragma unroll
      for (int j = 0; j < 4; j++) { s[i][j] = __expf(s[i][j] - newm); rs += s[i][j]; }
      #pragma unroll
      for (int off = 1; off < 16; off <<= 1) rs += __shfl_xor(rs, off);
      l_run[i] = l_run[i]*corr + rs;
      m_run[i] = newm;
      #pragma unroll
      for (int j = 0; j < 4; j++) ctxa[i][j] *= corr;
      #pragma unroll
      for (int j = 0; j < 4; j++) ps[swz(4*rg+i, 4*cg+j)] = s[i][j];
    }
    __syncthreads();   // P tile visible

    // ctx[4rg+i][4cg+jj] += sum_c P[r][c] * V[c][dd]
    for (int c4 = 0; c4 < 16; c4++) {
      float4 pv[4], vv[4];
      #pragma unroll
      for (int i = 0; i < 4; i++) pv[i] = *(const float4*)&ps[swz(4*rg+i, 4*c4)];
      #pragma unroll
      for (int j = 0; j < 4; j++) vv[j] = *(const float4*)&vs[swz(4*c4+j, 4*cg)];
      #pragma unroll
      for (int i = 0; i < 4; i++) {
        #define PVSTEP(PC, VJ) \
          ctxa[i][0] = fmaf(PC, VJ.x, ctxa[i][0]); \
          ctxa[i][1] = fmaf(PC, VJ.y, ctxa[i][1]); \
          ctxa[i][2] = fmaf(PC, VJ.z, ctxa[i][2]); \
          ctxa[i][3] = fmaf(PC, VJ.w, ctxa[i][3]);
        PVSTEP(pv[i].x, vv[0])
        PVSTEP(pv[i].y, vv[1])
        PVSTEP(pv[i].z, vv[2])
        PVSTEP(pv[i].w, vv[3])
        #undef PVSTEP
      }
    }
  }

  // epilogue: normalize and write ctx over the Q region (safe: region is
  // private to this block and Q was staged to LDS before any write)
  #pragma unroll
  for (int i = 0; i < 4; i++) {
    const float inv = 1.0f / l_run[i];
    float4 o;
    o.x = ctxa[i][0]*inv; o.y = ctxa[i][1]*inv;
    o.z = ctxa[i][2]*inv; o.w = ctxa[i][3]*inv;
    *(float4*)&QCTX[((long)b*NN + q0 + 4*rg + i)*HH + head*64 + 4*cg] = o;
  }
}

// h = LN(relu(ctx) + h) * gl + bl   (one wave per row)
__global__ __launch_bounds__(256) void resln_kernel(
    const float* __restrict__ CTX, float* Hb,
    const float* __restrict__ gl, const float* __restrict__ bl)
{
  const int t = threadIdx.x;
  const int lane = t & 63;
  const long row = (long)blockIdx.x*4 + (t >> 6);
  const float2 c2 = *(const float2*)&CTX[row*HH + lane*2];
  const float2 h2 = *(const float2*)&Hb[row*HH + lane*2];
  const float x0 = fmaxf(c2.x, 0.0f) + h2.x;
  const float x1 = fmaxf(c2.y, 0.0f) + h2.y;
  float s = x0 + x1, ss = x0*x0 + x1*x1;
  #pragma unroll
  for (int off = 1; off < 64; off <<= 1) {
    s  += __shfl_xor(s,  off);
    ss += __shfl_xor(ss, off);
  }
  const float mean = s * (1.0f/128.0f);
  const float rstd = rsqrtf(ss*(1.0f/128.0f) - mean*mean + 1e-5f);
  float2 o;
  o.x = (x0 - mean)*rstd*gl[lane*2]   + bl[lane*2];
  o.y = (x1 - mean)*rstd*gl[lane*2+1] + bl[lane*2+1];
  *(float2*)&Hb[row*HH + lane*2] = o;
}

// out[b, col] = max over n of h[b, n, col]
__global__ __launch_bounds__(256) void maxred_kernel(
    const float* __restrict__ Hb, float* __restrict__ out)
{
  __shared__ float red[256];
  const int b = blockIdx.x;
  const int col = threadIdx.x & 127, half = threadIdx.x >> 7;
  const float* hp = Hb + ((long)b*NN + half*256)*HH + col;
  float m0 = -3.0e38f, m1 = -3.0e38f, m2 = -3.0e38f, m3 = -3.0e38f;
  for (int r = 0; r < 256; r += 4) {
    m0 = fmaxf(m0, hp[(r+0)*HH]);
    m1 = fmaxf(m1, hp[(r+1)*HH]);
    m2 = fmaxf(m2, hp[(r+2)*HH]);
    m3 = fmaxf(m3, hp[(r+3)*HH]);
  }
  red[threadIdx.x] = fmaxf(fmaxf(m0, m1), fmaxf(m2, m3));
  __syncthreads();
  if (half == 0) out[(long)b*HH + col] = fmaxf(red[col], red[col + 128]);
}

extern "C" void kernel_launch(void* const* d_in, const int* in_sizes, int n_in,
                              void* d_out, int out_size, void* d_ws, size_t ws_size,
                              hipStream_t stream)
{
  const float* x   = (const float*)d_in[0];
  const int* lens  = (const int*)d_in[1];
  const float* W0  = (const float*)d_in[2];
  const float* b0  = (const float*)d_in[3];
  const float* g0  = (const float*)d_in[4];
  const float* be0 = (const float*)d_in[5];
  const float* W1  = (const float*)d_in[6];
  const float* b1  = (const float*)d_in[7];
  const float* g1  = (const float*)d_in[8];
  const float* be1 = (const float*)d_in[9];
  const float* Wq  = (const float*)d_in[10];
  const float* bq  = (const float*)d_in[11];
  const float* Wk  = (const float*)d_in[12];
  const float* bk  = (const float*)d_in[13];
  const float* Wv  = (const float*)d_in[14];
  const float* bv  = (const float*)d_in[15];
  const float* gl  = (const float*)d_in[16];
  const float* bl  = (const float*)d_in[17];
  float* out = (float*)d_out;

  float* h = (float*)d_ws;                 // [B*N, H]
  float* q = h + (size_t)MM*HH;            // [B*N, H], reused as ctx
  float* k = q + (size_t)MM*HH;
  float* v = k + (size_t)MM*HH;

  linear_kernel<true ><<<MM/32, 256, 0, stream>>>(x, W0, b0, g0, be0, h);
  linear_kernel<true ><<<MM/32, 256, 0, stream>>>(h, W1, b1, g1, be1, h);

  for (int d = 0; d < 3; d++) {
    linear_kernel<false><<<MM/32, 256, 0, stream>>>(h, Wq + d*HH*HH, bq + d*HH, nullptr, nullptr, q);
    linear_kernel<false><<<MM/32, 256, 0, stream>>>(h, Wk + d*HH*HH, bk + d*HH, nullptr, nullptr, k);
    linear_kernel<false><<<MM/32, 256, 0, stream>>>(h, Wv + d*HH*HH, bv + d*HH, nullptr, nullptr, v);
    attn_kernel<<<BB*2*8, 256, 0, stream>>>(q, k, v, lens);
    resln_kernel<<<MM/4, 256, 0, stream>>>(q, h, gl + d*HH, bl + d*HH);
  }
  maxred_kernel<<<BB, 256, 0, stream>>>(h, out);
}

// Round 2
// 1844.816 us; speedup vs baseline: 1.6868x; 1.6868x over previous
//
#include <hip/hip_runtime.h>
#include <hip/hip_bf16.h>

#define BB 256
#define NN 512
#define HH 128
#define MM (BB*NN)

typedef unsigned short u16;
typedef __attribute__((ext_vector_type(8))) short bf16x8;   // 8 bf16 (4 VGPRs)
typedef __attribute__((ext_vector_type(4))) float f32x4;

// byte offset of (row, cbyte) in a [*][64]bf16 (128B-row) LDS tile, XOR-swizzled
__device__ __forceinline__ int kswz(int row, int cbyte) {
  return row*128 + (cbyte ^ ((row & 7) << 4));
}

__device__ __forceinline__ u16 f2bf(float x) {   // f32 -> bf16 RNE
  unsigned u = __float_as_uint(x);
  return (u16)((u + 0x7fffu + ((u >> 16) & 1u)) >> 16);
}

// ---------------------------------------------------------------------------
// OUT[M,128] = (LNRELU ? relu(LN(X@W + b)) : X@W + b); optional bf16 output.
// 32 rows per block, 256 threads. Safe for X == OUT (tile staged in LDS).
template<bool LNRELU, bool BF16OUT>
__global__ __launch_bounds__(256) void linear_kernel(
    const float* X, const float* __restrict__ W,
    const float* __restrict__ bias, const float* __restrict__ gamma,
    const float* __restrict__ beta, void* OUTv)
{
  __shared__ float ws[HH*HH];   // W[k][c]  64KB
  __shared__ float xs[32*HH];   // x tile / out tile  16KB
  const int t = threadIdx.x;
  const long rowbase = (long)blockIdx.x * 32;

  for (int i = 0; i < HH*HH/256; i++) ws[t + 256*i] = W[t + 256*i];
  const float* xp = X + rowbase*HH;
  for (int i = 0; i < 32*HH/256; i++) xs[t + 256*i] = xp[t + 256*i];
  __syncthreads();

  const int c  = t & 127;     // output column
  const int rh = t >> 7;      // row parity; thread owns rows rh, rh+2, ... (16 rows)
  float acc[16];
  const float bc = bias[c];
  #pragma unroll
  for (int j = 0; j < 16; j++) acc[j] = bc;

  for (int k = 0; k < HH; k += 4) {
    const float w0 = ws[(k+0)*HH + c];
    const float w1 = ws[(k+1)*HH + c];
    const float w2 = ws[(k+2)*HH + c];
    const float w3 = ws[(k+3)*HH + c];
    #pragma unroll
    for (int j = 0; j < 16; j++) {
      const float4 x4 = *(const float4*)&xs[(rh + 2*j)*HH + k];
      acc[j] = fmaf(x4.x, w0, acc[j]);
      acc[j] = fmaf(x4.y, w1, acc[j]);
      acc[j] = fmaf(x4.z, w2, acc[j]);
      acc[j] = fmaf(x4.w, w3, acc[j]);
    }
  }

  if constexpr (!LNRELU) {
    if constexpr (BF16OUT) {
      u16* op = (u16*)OUTv + rowbase*HH;
      #pragma unroll
      for (int j = 0; j < 16; j++) op[(rh + 2*j)*HH + c] = f2bf(acc[j]);
    } else {
      float* op = (float*)OUTv + rowbase*HH;
      #pragma unroll
      for (int j = 0; j < 16; j++) op[(rh + 2*j)*HH + c] = acc[j];
    }
  } else {
    float* OUT = (float*)OUTv;
    __syncthreads();                       // xs reads done everywhere
    #pragma unroll
    for (int j = 0; j < 16; j++) xs[(rh + 2*j)*HH + c] = acc[j];
    __syncthreads();
    const int wave = t >> 6, lane = t & 63;
    const float g0 = gamma[lane*2],   g1 = gamma[lane*2+1];
    const float p0 = beta[lane*2],    p1 = beta[lane*2+1];
    for (int r = wave; r < 32; r += 4) {
      const float2 v2 = *(const float2*)&xs[r*HH + lane*2];
      float s  = v2.x + v2.y;
      float ss = v2.x*v2.x + v2.y*v2.y;
      #pragma unroll
      for (int off = 1; off < 64; off <<= 1) {
        s  += __shfl_xor(s,  off);
        ss += __shfl_xor(ss, off);
      }
      const float mean = s * (1.0f/128.0f);
      const float var  = ss * (1.0f/128.0f) - mean*mean;
      const float rstd = rsqrtf(var + 1e-5f);
      float2 o;
      o.x = fmaxf((v2.x - mean)*rstd*g0 + p0, 0.0f);
      o.y = fmaxf((v2.y - mean)*rstd*g1 + p1, 0.0f);
      *(float2*)&OUT[(rowbase + r)*HH + lane*2] = o;
    }
  }
}

// ---------------------------------------------------------------------------
// v[B*N][128] bf16  ->  vT[(b*2+head)*64 + dh][512] bf16
__global__ __launch_bounds__(256) void transpose_v_kernel(
    const u16* __restrict__ vb, u16* __restrict__ vT)
{
  __shared__ u16 tile[128*128];   // 32KB, slot-XOR swizzled
  const int t  = threadIdx.x;
  const int b  = blockIdx.x >> 2;
  const int n0 = (blockIdx.x & 3) * 128;

  // load 128 rows (n) x 128 cols (c): 2048 chunks of 16B
  #pragma unroll
  for (int i = 0; i < 8; i++) {
    const int chunk = t + 256*i;
    const int n = chunk >> 4, cslot = chunk & 15;
    uint4 d = *(const uint4*)(vb + ((size_t)(b*NN + n0 + n))*HH + cslot*8);
    *(uint4*)&tile[n*128 + ((cslot ^ ((n>>3)&7)) << 3)] = d;
  }
  __syncthreads();

  // write transposed: out row = hidden col c; pack 8 consecutive n per store
  #pragma unroll
  for (int i = 0; i < 8; i++) {
    const int chunk = t + 256*i;
    const int c = chunk >> 4, nb = (chunk & 15) * 8;
    union { u16 s[8]; uint4 v; } u;
    #pragma unroll
    for (int j = 0; j < 8; j++) {
      const int n = nb + j;
      u.s[j] = tile[n*128 + ((((c>>3) ^ ((n>>3)&7)) << 3) | (c & 7))];
    }
    u16* op = vT + (((size_t)(b*2 + (c>>6)))*64 + (c & 63))*NN + n0 + nb;
    *(uint4*)op = u.v;
  }
}

// ---------------------------------------------------------------------------
// Flash attention, bf16 MFMA. Block = (b, head, 128-row q-tile), 4 waves.
__global__ __launch_bounds__(256) void attn_kernel(
    const u16* __restrict__ Q, const u16* __restrict__ K,
    const u16* __restrict__ VT, const int* __restrict__ lengths,
    float* __restrict__ CTX)
{
  __shared__ u16 sh_k[64*64];     // K chunk  [key][dh]   8KB
  __shared__ u16 sh_v[64*64];     // VT chunk [dh][key]   8KB
  __shared__ u16 sh_pq[128*64];   // Q staging, then per-wave P [32][key] 16KB
  const int t    = threadIdx.x;
  const int lane = t & 63;
  const int w    = t >> 6;
  const int bid  = blockIdx.x;
  const int qt   = bid & 3;
  const int head = (bid >> 2) & 1;
  const int b    = bid >> 3;
  const int L    = lengths[b];
  const int q0   = qt * 128;
  const int l4 = lane >> 4, l15 = lane & 15;

  // ---- stage Q[128][64] (swizzled) ----
  {
    const char* qbase = (const char*)(Q + ((size_t)(b*NN + q0))*HH + head*64);
    #pragma unroll
    for (int i = 0; i < 4; i++) {
      const int chunk = t + 256*i;          // 1024 x 16B
      const int r = chunk >> 3, cb = (chunk & 7) * 16;
      uint4 d = *(const uint4*)(qbase + (size_t)r*256 + cb);
      *(uint4*)((char*)sh_pq + kswz(r, cb)) = d;
    }
  }
  __syncthreads();

  // ---- Q fragments (each wave reads only its own 32 rows) ----
  bf16x8 qf[2][2];
  #pragma unroll
  for (int m = 0; m < 2; m++)
    #pragma unroll
    for (int ks = 0; ks < 2; ks++)
      qf[m][ks] = *(const bf16x8*)((const char*)sh_pq +
                    kswz(w*32 + m*16 + l15, ks*64 + l4*16));

  u16* p_lds = sh_pq + w*2048;    // this wave's P region [32][64]

  float m_run[2][4], l_run[2][4];
  f32x4 ctxa[2][4];
  #pragma unroll
  for (int m = 0; m < 2; m++)
    #pragma unroll
    for (int r = 0; r < 4; r++) {
      m_run[m][r] = -3.0e38f; l_run[m][r] = 0.0f;
      ctxa[m][0][r] = 0.f; ctxa[m][1][r] = 0.f; ctxa[m][2][r] = 0.f; ctxa[m][3][r] = 0.f;
    }

  for (int ch = 0; ch < 8; ch++) {
    __syncthreads();   // previous chunk's k/v reads done (also covers qf reads)
    {
      const char* kbase = (const char*)(K  + ((size_t)(b*NN + ch*64))*HH + head*64);
      const char* vbase = (const char*)(VT + (((size_t)(b*2 + head))*64)*NN + ch*64);
      #pragma unroll
      for (int i = 0; i < 2; i++) {
        const int chunk = t + 256*i;        // 512 x 16B each
        const int r = chunk >> 3, cb = (chunk & 7) * 16;
        uint4 dk = *(const uint4*)(kbase + (size_t)r*256  + cb);
        uint4 dv = *(const uint4*)(vbase + (size_t)r*1024 + cb);
        *(uint4*)((char*)sh_k + kswz(r, cb)) = dk;
        *(uint4*)((char*)sh_v + kswz(r, cb)) = dv;
      }
    }
    __syncthreads();

    // ---- S = Q K^T ----
    f32x4 acc[2][4];
    #pragma unroll
    for (int m = 0; m < 2; m++)
      #pragma unroll
      for (int n = 0; n < 4; n++)
        { acc[m][n][0]=0.f; acc[m][n][1]=0.f; acc[m][n][2]=0.f; acc[m][n][3]=0.f; }
    #pragma unroll
    for (int ks = 0; ks < 2; ks++) {
      bf16x8 kf[4];
      #pragma unroll
      for (int n = 0; n < 4; n++)
        kf[n] = *(const bf16x8*)((const char*)sh_k + kswz(n*16 + l15, ks*64 + l4*16));
      #pragma unroll
      for (int m = 0; m < 2; m++)
        #pragma unroll
        for (int n = 0; n < 4; n++)
          acc[m][n] = __builtin_amdgcn_mfma_f32_16x16x32_bf16(
                        qf[m][ks], kf[n], acc[m][n], 0, 0, 0);
    }

    // ---- mask + online softmax (C-layout: col=l15 key, row=l4*4+r) ----
    float kb[4];
    #pragma unroll
    for (int n = 0; n < 4; n++)
      kb[n] = (ch*64 + n*16 + l15 < L) ? 0.0f : -10000.0f;

    #pragma unroll
    for (int m = 0; m < 2; m++) {
      #pragma unroll
      for (int r = 0; r < 4; r++) {
        const int qrow = q0 + w*32 + m*16 + l4*4 + r;
        const bool qv = qrow < L;    // invalid q-row: uniform bias, cancels
        float s0 = acc[m][0][r]*0.125f + (qv ? kb[0] : 0.0f);
        float s1 = acc[m][1][r]*0.125f + (qv ? kb[1] : 0.0f);
        float s2 = acc[m][2][r]*0.125f + (qv ? kb[2] : 0.0f);
        float s3 = acc[m][3][r]*0.125f + (qv ? kb[3] : 0.0f);
        float mx = fmaxf(fmaxf(s0, s1), fmaxf(s2, s3));
        #pragma unroll
        for (int off = 1; off < 16; off <<= 1) mx = fmaxf(mx, __shfl_xor(mx, off));
        const float newm = fmaxf(m_run[m][r], mx);
        const float corr = __expf(m_run[m][r] - newm);
        m_run[m][r] = newm;
        s0 = __expf(s0 - newm); s1 = __expf(s1 - newm);
        s2 = __expf(s2 - newm); s3 = __expf(s3 - newm);
        float rs = (s0 + s1) + (s2 + s3);
        #pragma unroll
        for (int off = 1; off < 16; off <<= 1) rs += __shfl_xor(rs, off);
        l_run[m][r] = l_run[m][r]*corr + rs;
        ctxa[m][0][r] *= corr; ctxa[m][1][r] *= corr;
        ctxa[m][2][r] *= corr; ctxa[m][3][r] *= corr;
        const int prow = m*16 + l4*4 + r;
        u16* pr = (u16*)((char*)p_lds + prow*128);
        pr[(((0*16 + l15)*2) ^ ((prow&7)<<4)) >> 1] = f2bf(s0);
        pr[(((1*16 + l15)*2) ^ ((prow&7)<<4)) >> 1] = f2bf(s1);
        pr[(((2*16 + l15)*2) ^ ((prow&7)<<4)) >> 1] = f2bf(s2);
        pr[(((3*16 + l15)*2) ^ ((prow&7)<<4)) >> 1] = f2bf(s3);
      }
    }

    // ---- ctx += P V  (A = P rows q, B = V^T rows dh) ----
    #pragma unroll
    for (int ks = 0; ks < 2; ks++) {
      bf16x8 pa[2], vbf[4];
      #pragma unroll
      for (int m = 0; m < 2; m++)
        pa[m] = *(const bf16x8*)((const char*)p_lds + kswz(m*16 + l15, ks*64 + l4*16));
      #pragma unroll
      for (int d = 0; d < 4; d++)
        vbf[d] = *(const bf16x8*)((const char*)sh_v + kswz(d*16 + l15, ks*64 + l4*16));
      #pragma unroll
      for (int m = 0; m < 2; m++)
        #pragma unroll
        for (int d = 0; d < 4; d++)
          ctxa[m][d] = __builtin_amdgcn_mfma_f32_16x16x32_bf16(
                         pa[m], vbf[d], ctxa[m][d], 0, 0, 0);
    }
  }

  // ---- epilogue ----
  #pragma unroll
  for (int m = 0; m < 2; m++)
    #pragma unroll
    for (int r = 0; r < 4; r++) {
      const int qrow = q0 + w*32 + m*16 + l4*4 + r;
      const float inv = 1.0f / l_run[m][r];
      float* crow = CTX + ((size_t)(b*NN) + qrow)*HH + head*64 + l15;
      crow[0]  = ctxa[m][0][r]*inv;
      crow[16] = ctxa[m][1][r]*inv;
      crow[32] = ctxa[m][2][r]*inv;
      crow[48] = ctxa[m][3][r]*inv;
    }
}

// ---------------------------------------------------------------------------
__global__ __launch_bounds__(256) void resln_kernel(
    const float* __restrict__ CTX, float* Hb,
    const float* __restrict__ gl, const float* __restrict__ bl)
{
  const int t = threadIdx.x;
  const int lane = t & 63;
  const long row = (long)blockIdx.x*4 + (t >> 6);
  const float2 c2 = *(const float2*)&CTX[row*HH + lane*2];
  const float2 h2 = *(const float2*)&Hb[row*HH + lane*2];
  const float x0 = fmaxf(c2.x, 0.0f) + h2.x;
  const float x1 = fmaxf(c2.y, 0.0f) + h2.y;
  float s = x0 + x1, ss = x0*x0 + x1*x1;
  #pragma unroll
  for (int off = 1; off < 64; off <<= 1) {
    s  += __shfl_xor(s,  off);
    ss += __shfl_xor(ss, off);
  }
  const float mean = s * (1.0f/128.0f);
  const float rstd = rsqrtf(ss*(1.0f/128.0f) - mean*mean + 1e-5f);
  float2 o;
  o.x = (x0 - mean)*rstd*gl[lane*2]   + bl[lane*2];
  o.y = (x1 - mean)*rstd*gl[lane*2+1] + bl[lane*2+1];
  *(float2*)&Hb[row*HH + lane*2] = o;
}

__global__ __launch_bounds__(256) void maxred_kernel(
    const float* __restrict__ Hb, float* __restrict__ out)
{
  __shared__ float red[256];
  const int b = blockIdx.x;
  const int col = threadIdx.x & 127, half = threadIdx.x >> 7;
  const float* hp = Hb + ((long)b*NN + half*256)*HH + col;
  float m0 = -3.0e38f, m1 = -3.0e38f, m2 = -3.0e38f, m3 = -3.0e38f;
  for (int r = 0; r < 256; r += 4) {
    m0 = fmaxf(m0, hp[(r+0)*HH]);
    m1 = fmaxf(m1, hp[(r+1)*HH]);
    m2 = fmaxf(m2, hp[(r+2)*HH]);
    m3 = fmaxf(m3, hp[(r+3)*HH]);
  }
  red[threadIdx.x] = fmaxf(fmaxf(m0, m1), fmaxf(m2, m3));
  __syncthreads();
  if (half == 0) out[(long)b*HH + col] = fmaxf(red[col], red[col + 128]);
}

// ---------------------------------------------------------------------------
extern "C" void kernel_launch(void* const* d_in, const int* in_sizes, int n_in,
                              void* d_out, int out_size, void* d_ws, size_t ws_size,
                              hipStream_t stream)
{
  const float* x   = (const float*)d_in[0];
  const int* lens  = (const int*)d_in[1];
  const float* W0  = (const float*)d_in[2];
  const float* b0  = (const float*)d_in[3];
  const float* g0  = (const float*)d_in[4];
  const float* be0 = (const float*)d_in[5];
  const float* W1  = (const float*)d_in[6];
  const float* b1  = (const float*)d_in[7];
  const float* g1  = (const float*)d_in[8];
  const float* be1 = (const float*)d_in[9];
  const float* Wq  = (const float*)d_in[10];
  const float* bq  = (const float*)d_in[11];
  const float* Wk  = (const float*)d_in[12];
  const float* bk  = (const float*)d_in[13];
  const float* Wv  = (const float*)d_in[14];
  const float* bv  = (const float*)d_in[15];
  const float* gl  = (const float*)d_in[16];
  const float* bl  = (const float*)d_in[17];
  float* out = (float*)d_out;

  float* h   = (float*)d_ws;               // 64MB
  float* ctx = h + (size_t)MM*HH;          // 64MB
  u16* qb = (u16*)(ctx + (size_t)MM*HH);   // 32MB
  u16* kb = qb + (size_t)MM*HH;            // 32MB
  u16* vb = kb + (size_t)MM*HH;            // 32MB
  u16* vT = vb + (size_t)MM*HH;            // 32MB

  linear_kernel<true,false><<<MM/32, 256, 0, stream>>>(x, W0, b0, g0, be0, h);
  linear_kernel<true,false><<<MM/32, 256, 0, stream>>>(h, W1, b1, g1, be1, h);

  for (int d = 0; d < 3; d++) {
    linear_kernel<false,true><<<MM/32, 256, 0, stream>>>(h, Wq + d*HH*HH, bq + d*HH, nullptr, nullptr, qb);
    linear_kernel<false,true><<<MM/32, 256, 0, stream>>>(h, Wk + d*HH*HH, bk + d*HH, nullptr, nullptr, kb);
    linear_kernel<false,true><<<MM/32, 256, 0, stream>>>(h, Wv + d*HH*HH, bv + d*HH, nullptr, nullptr, vb);
    transpose_v_kernel<<<BB*4, 256, 0, stream>>>(vb, vT);
    attn_kernel<<<BB*2*4, 256, 0, stream>>>(qb, kb, vT, lens, ctx);
    resln_kernel<<<MM/4, 256, 0, stream>>>(ctx, h, gl + d*HH, bl + d*HH);
  }
  maxred_kernel<<<BB, 256, 0, stream>>>(h, out);
}

// Round 4
// 749.064 us; speedup vs baseline: 4.1542x; 2.4628x over previous
//
#include <hip/hip_runtime.h>
#include <hip/hip_bf16.h>

#define BB 256
#define NN 512
#define HH 128
#define MM (BB*NN)

typedef unsigned short u16;
typedef unsigned int   u32;
typedef __attribute__((ext_vector_type(8))) short bf16x8;   // 8 bf16 (4 VGPRs)
typedef __attribute__((ext_vector_type(4))) float f32x4;

// byte offset of (row, cbyte) in a [*][64]bf16 (128B-row) LDS tile, XOR-swizzled
__device__ __forceinline__ int kswz(int row, int cbyte) {
  return row*128 + (cbyte ^ ((row & 7) << 4));
}
// same for [*][128]bf16 (256B-row) tiles
__device__ __forceinline__ int wswz(int row, int cbyte) {
  return row*256 + (cbyte ^ ((row & 7) << 4));
}

__device__ __forceinline__ u16 f2bf(float x) {   // f32 -> bf16 RNE
  unsigned u = __float_as_uint(x);
  return (u16)((u + 0x7fffu + ((u >> 16) & 1u)) >> 16);
}
__device__ __forceinline__ float bf2f(u16 x) {
  return __uint_as_float(((u32)x) << 16);
}

// ---------------------------------------------------------------------------
// Pre-transpose + bf16-convert the 11 weight matrices: wt[i] = W_i^T [c][k]
__global__ __launch_bounds__(256) void wt_prep(
    const float* __restrict__ W0, const float* __restrict__ W1,
    const float* __restrict__ Wq, const float* __restrict__ Wk,
    const float* __restrict__ Wv, u16* __restrict__ wt)
{
  __shared__ u16 tile[128*128];
  const int t = threadIdx.x;
  const int i = blockIdx.x;
  const float* src;
  if (i == 0) src = W0;
  else if (i == 1) src = W1;
  else {
    const int d = (i-2)/3, which = (i-2)%3;
    src = (which==0 ? Wq : which==1 ? Wk : Wv) + d*HH*HH;
  }
  u16* dst = wt + (size_t)i*HH*HH;

  #pragma unroll
  for (int j = 0; j < 8; j++) {
    const int chunk = t + 256*j;
    const int k = chunk >> 4, c8 = (chunk & 15)*8;
    const float4 a = *(const float4*)&src[k*HH + c8];
    const float4 b = *(const float4*)&src[k*HH + c8 + 4];
    union { u16 s[8]; uint4 v; } u;
    u.s[0]=f2bf(a.x); u.s[1]=f2bf(a.y); u.s[2]=f2bf(a.z); u.s[3]=f2bf(a.w);
    u.s[4]=f2bf(b.x); u.s[5]=f2bf(b.y); u.s[6]=f2bf(b.z); u.s[7]=f2bf(b.w);
    *(uint4*)&tile[k*128 + (((chunk & 15) ^ ((k>>3)&7)) << 3)] = u.v;
  }
  __syncthreads();
  #pragma unroll
  for (int j = 0; j < 8; j++) {
    const int chunk = t + 256*j;
    const int c = chunk >> 4, kb8 = (chunk & 15)*8;
    union { u16 s[8]; uint4 v; } u;
    #pragma unroll
    for (int e = 0; e < 8; e++) {
      const int k = kb8 + e;
      u.s[e] = tile[k*128 + ((((c>>3) ^ ((k>>3)&7)) << 3) | (c & 7))];
    }
    *(uint4*)&dst[c*HH + kb8] = u.v;
  }
}

// ---------------------------------------------------------------------------
// OUT[M,128](bf16) = LNRELU ? relu(LN(X@W + b)) : X@W + b.  MFMA version.
// 128 rows/block, 4 waves x 32 rows. WT is bf16 W^T [c][k]. X==OUT safe.
template<bool F32IN, bool LNRELU>
__global__ __launch_bounds__(256) void linear_mfma(
    const void* __restrict__ Xv, const u16* __restrict__ WT,
    const float* __restrict__ bias, const float* __restrict__ gamma,
    const float* __restrict__ beta, u16* __restrict__ OUT)
{
  __shared__ u16 wt_s[128*128];  // W^T tile, swizzled 32KB
  __shared__ u16 xs[128*128];    // X tile,   swizzled 32KB
  const int t = threadIdx.x;
  const int lane = t & 63, w = t >> 6;
  const int l4 = lane >> 4, l15 = lane & 15;
  const long row0 = (long)blockIdx.x * 128;

  // stage W^T (2048 x 16B chunks)
  #pragma unroll
  for (int i = 0; i < 8; i++) {
    const int chunk = t + 256*i;
    const int r = chunk >> 4, cb = (chunk & 15)*16;
    uint4 d = *(const uint4*)((const char*)WT + (size_t)r*256 + cb);
    *(uint4*)((char*)wt_s + wswz(r, cb)) = d;
  }
  // stage X
  if constexpr (F32IN) {
    const float* xp = (const float*)Xv + row0*HH;
    #pragma unroll
    for (int i = 0; i < 8; i++) {
      const int chunk = t + 256*i;
      const int r = chunk >> 4, c8 = (chunk & 15)*8;
      const float4 a = *(const float4*)&xp[r*HH + c8];
      const float4 b = *(const float4*)&xp[r*HH + c8 + 4];
      union { u16 s[8]; uint4 v; } u;
      u.s[0]=f2bf(a.x); u.s[1]=f2bf(a.y); u.s[2]=f2bf(a.z); u.s[3]=f2bf(a.w);
      u.s[4]=f2bf(b.x); u.s[5]=f2bf(b.y); u.s[6]=f2bf(b.z); u.s[7]=f2bf(b.w);
      *(uint4*)((char*)xs + wswz(r, c8*2)) = u.v;
    }
  } else {
    const u16* xp = (const u16*)Xv + row0*HH;
    #pragma unroll
    for (int i = 0; i < 8; i++) {
      const int chunk = t + 256*i;
      const int r = chunk >> 4, cb = (chunk & 15)*16;
      uint4 d = *(const uint4*)((const char*)xp + (size_t)r*256 + cb);
      *(uint4*)((char*)xs + wswz(r, cb)) = d;
    }
  }
  __syncthreads();

  f32x4 acc[2][8];
  #pragma unroll
  for (int m = 0; m < 2; m++)
    #pragma unroll
    for (int n = 0; n < 8; n++)
      { acc[m][n][0]=0.f; acc[m][n][1]=0.f; acc[m][n][2]=0.f; acc[m][n][3]=0.f; }

  #pragma unroll
  for (int ks = 0; ks < 4; ks++) {
    bf16x8 af[2], bf[8];
    #pragma unroll
    for (int m = 0; m < 2; m++)
      af[m] = *(const bf16x8*)((const char*)xs + wswz(w*32 + m*16 + l15, ks*64 + l4*16));
    #pragma unroll
    for (int n = 0; n < 8; n++)
      bf[n] = *(const bf16x8*)((const char*)wt_s + wswz(n*16 + l15, ks*64 + l4*16));
    #pragma unroll
    for (int m = 0; m < 2; m++)
      #pragma unroll
      for (int n = 0; n < 8; n++)
        acc[m][n] = __builtin_amdgcn_mfma_f32_16x16x32_bf16(af[m], bf[n], acc[m][n], 0, 0, 0);
  }

  // epilogue: bias (+LN+ReLU), bf16 store.  C layout: row=m*16+l4*4+r, col=n*16+l15
  float bia[8], gam[8], bet[8];
  #pragma unroll
  for (int n = 0; n < 8; n++) {
    bia[n] = bias[n*16 + l15];
    if constexpr (LNRELU) { gam[n] = gamma[n*16 + l15]; bet[n] = beta[n*16 + l15]; }
  }
  #pragma unroll
  for (int m = 0; m < 2; m++) {
    #pragma unroll
    for (int r = 0; r < 4; r++) {
      const long row = row0 + w*32 + m*16 + l4*4 + r;
      float v[8];
      #pragma unroll
      for (int n = 0; n < 8; n++) v[n] = acc[m][n][r] + bia[n];
      if constexpr (LNRELU) {
        float s = 0.f, ss = 0.f;
        #pragma unroll
        for (int n = 0; n < 8; n++) { s += v[n]; ss += v[n]*v[n]; }
        #pragma unroll
        for (int off = 1; off < 16; off <<= 1) {
          s  += __shfl_xor(s,  off);
          ss += __shfl_xor(ss, off);
        }
        const float mean = s * (1.0f/128.0f);
        const float rstd = rsqrtf(ss*(1.0f/128.0f) - mean*mean + 1e-5f);
        #pragma unroll
        for (int n = 0; n < 8; n++)
          v[n] = fmaxf((v[n] - mean)*rstd*gam[n] + bet[n], 0.0f);
      }
      u16* op = OUT + row*HH + l15;
      #pragma unroll
      for (int n = 0; n < 8; n++) op[n*16] = f2bf(v[n]);
    }
  }
}

// ---------------------------------------------------------------------------
// v[B*N][128] bf16  ->  vT[(b*2+head)*64 + dh][512] bf16
__global__ __launch_bounds__(256) void transpose_v_kernel(
    const u16* __restrict__ vb, u16* __restrict__ vT)
{
  __shared__ u16 tile[128*128];
  const int t  = threadIdx.x;
  const int b  = blockIdx.x >> 2;
  const int n0 = (blockIdx.x & 3) * 128;

  #pragma unroll
  for (int i = 0; i < 8; i++) {
    const int chunk = t + 256*i;
    const int n = chunk >> 4, cslot = chunk & 15;
    uint4 d = *(const uint4*)(vb + ((size_t)(b*NN + n0 + n))*HH + cslot*8);
    *(uint4*)&tile[n*128 + ((cslot ^ ((n>>3)&7)) << 3)] = d;
  }
  __syncthreads();
  #pragma unroll
  for (int i = 0; i < 8; i++) {
    const int chunk = t + 256*i;
    const int c = chunk >> 4, nb = (chunk & 15) * 8;
    union { u16 s[8]; uint4 v; } u;
    #pragma unroll
    for (int j = 0; j < 8; j++) {
      const int n = nb + j;
      u.s[j] = tile[n*128 + ((((c>>3) ^ ((n>>3)&7)) << 3) | (c & 7))];
    }
    u16* op = vT + (((size_t)(b*2 + (c>>6)))*64 + (c & 63))*NN + n0 + nb;
    *(uint4*)op = u.v;
  }
}

// ---------------------------------------------------------------------------
// Flash attention, bf16 MFMA. Block = (b, head, 128-row q-tile), 4 waves.
__global__ __launch_bounds__(256) void attn_kernel(
    const u16* __restrict__ Q, const u16* __restrict__ K,
    const u16* __restrict__ VT, const int* __restrict__ lengths,
    float* __restrict__ CTX)
{
  __shared__ u16 sh_k[64*64];
  __shared__ u16 sh_v[64*64];
  __shared__ u16 sh_pq[128*64];
  const int t    = threadIdx.x;
  const int lane = t & 63;
  const int w    = t >> 6;
  const int bid  = blockIdx.x;
  const int qt   = bid & 3;
  const int head = (bid >> 2) & 1;
  const int b    = bid >> 3;
  const int L    = lengths[b];
  const int q0   = qt * 128;
  const int l4 = lane >> 4, l15 = lane & 15;

  {
    const char* qbase = (const char*)(Q + ((size_t)(b*NN + q0))*HH + head*64);
    #pragma unroll
    for (int i = 0; i < 4; i++) {
      const int chunk = t + 256*i;
      const int r = chunk >> 3, cb = (chunk & 7) * 16;
      uint4 d = *(const uint4*)(qbase + (size_t)r*256 + cb);
      *(uint4*)((char*)sh_pq + kswz(r, cb)) = d;
    }
  }
  __syncthreads();

  bf16x8 qf[2][2];
  #pragma unroll
  for (int m = 0; m < 2; m++)
    #pragma unroll
    for (int ks = 0; ks < 2; ks++)
      qf[m][ks] = *(const bf16x8*)((const char*)sh_pq +
                    kswz(w*32 + m*16 + l15, ks*64 + l4*16));

  u16* p_lds = sh_pq + w*2048;

  float m_run[2][4], l_run[2][4];
  f32x4 ctxa[2][4];
  #pragma unroll
  for (int m = 0; m < 2; m++)
    #pragma unroll
    for (int r = 0; r < 4; r++) {
      m_run[m][r] = -3.0e38f; l_run[m][r] = 0.0f;
      ctxa[m][0][r] = 0.f; ctxa[m][1][r] = 0.f; ctxa[m][2][r] = 0.f; ctxa[m][3][r] = 0.f;
    }

  for (int ch = 0; ch < 8; ch++) {
    __syncthreads();
    {
      const char* kbase = (const char*)(K  + ((size_t)(b*NN + ch*64))*HH + head*64);
      const char* vbase = (const char*)(VT + (((size_t)(b*2 + head))*64)*NN + ch*64);
      #pragma unroll
      for (int i = 0; i < 2; i++) {
        const int chunk = t + 256*i;
        const int r = chunk >> 3, cb = (chunk & 7) * 16;
        uint4 dk = *(const uint4*)(kbase + (size_t)r*256  + cb);
        uint4 dv = *(const uint4*)(vbase + (size_t)r*1024 + cb);
        *(uint4*)((char*)sh_k + kswz(r, cb)) = dk;
        *(uint4*)((char*)sh_v + kswz(r, cb)) = dv;
      }
    }
    __syncthreads();

    f32x4 acc[2][4];
    #pragma unroll
    for (int m = 0; m < 2; m++)
      #pragma unroll
      for (int n = 0; n < 4; n++)
        { acc[m][n][0]=0.f; acc[m][n][1]=0.f; acc[m][n][2]=0.f; acc[m][n][3]=0.f; }
    #pragma unroll
    for (int ks = 0; ks < 2; ks++) {
      bf16x8 kf[4];
      #pragma unroll
      for (int n = 0; n < 4; n++)
        kf[n] = *(const bf16x8*)((const char*)sh_k + kswz(n*16 + l15, ks*64 + l4*16));
      #pragma unroll
      for (int m = 0; m < 2; m++)
        #pragma unroll
        for (int n = 0; n < 4; n++)
          acc[m][n] = __builtin_amdgcn_mfma_f32_16x16x32_bf16(
                        qf[m][ks], kf[n], acc[m][n], 0, 0, 0);
    }

    float kb[4];
    #pragma unroll
    for (int n = 0; n < 4; n++)
      kb[n] = (ch*64 + n*16 + l15 < L) ? 0.0f : -10000.0f;

    #pragma unroll
    for (int m = 0; m < 2; m++) {
      #pragma unroll
      for (int r = 0; r < 4; r++) {
        const int qrow = q0 + w*32 + m*16 + l4*4 + r;
        const bool qv = qrow < L;
        float s0 = acc[m][0][r]*0.125f + (qv ? kb[0] : 0.0f);
        float s1 = acc[m][1][r]*0.125f + (qv ? kb[1] : 0.0f);
        float s2 = acc[m][2][r]*0.125f + (qv ? kb[2] : 0.0f);
        float s3 = acc[m][3][r]*0.125f + (qv ? kb[3] : 0.0f);
        float mx = fmaxf(fmaxf(s0, s1), fmaxf(s2, s3));
        #pragma unroll
        for (int off = 1; off < 16; off <<= 1) mx = fmaxf(mx, __shfl_xor(mx, off));
        const float newm = fmaxf(m_run[m][r], mx);
        const float corr = __expf(m_run[m][r] - newm);
        m_run[m][r] = newm;
        s0 = __expf(s0 - newm); s1 = __expf(s1 - newm);
        s2 = __expf(s2 - newm); s3 = __expf(s3 - newm);
        float rs = (s0 + s1) + (s2 + s3);
        #pragma unroll
        for (int off = 1; off < 16; off <<= 1) rs += __shfl_xor(rs, off);
        l_run[m][r] = l_run[m][r]*corr + rs;
        ctxa[m][0][r] *= corr; ctxa[m][1][r] *= corr;
        ctxa[m][2][r] *= corr; ctxa[m][3][r] *= corr;
        const int prow = m*16 + l4*4 + r;
        u16* pr = (u16*)((char*)p_lds + prow*128);
        pr[(((0*16 + l15)*2) ^ ((prow&7)<<4)) >> 1] = f2bf(s0);
        pr[(((1*16 + l15)*2) ^ ((prow&7)<<4)) >> 1] = f2bf(s1);
        pr[(((2*16 + l15)*2) ^ ((prow&7)<<4)) >> 1] = f2bf(s2);
        pr[(((3*16 + l15)*2) ^ ((prow&7)<<4)) >> 1] = f2bf(s3);
      }
    }

    #pragma unroll
    for (int ks = 0; ks < 2; ks++) {
      bf16x8 pa[2], vbf[4];
      #pragma unroll
      for (int m = 0; m < 2; m++)
        pa[m] = *(const bf16x8*)((const char*)p_lds + kswz(m*16 + l15, ks*64 + l4*16));
      #pragma unroll
      for (int d = 0; d < 4; d++)
        vbf[d] = *(const bf16x8*)((const char*)sh_v + kswz(d*16 + l15, ks*64 + l4*16));
      #pragma unroll
      for (int m = 0; m < 2; m++)
        #pragma unroll
        for (int d = 0; d < 4; d++)
          ctxa[m][d] = __builtin_amdgcn_mfma_f32_16x16x32_bf16(
                         pa[m], vbf[d], ctxa[m][d], 0, 0, 0);
    }
  }

  #pragma unroll
  for (int m = 0; m < 2; m++)
    #pragma unroll
    for (int r = 0; r < 4; r++) {
      const int qrow = q0 + w*32 + m*16 + l4*4 + r;
      const float inv = 1.0f / l_run[m][r];
      float* crow = CTX + ((size_t)(b*NN) + qrow)*HH + head*64 + l15;
      crow[0]  = ctxa[m][0][r]*inv;
      crow[16] = ctxa[m][1][r]*inv;
      crow[32] = ctxa[m][2][r]*inv;
      crow[48] = ctxa[m][3][r]*inv;
    }
}

// ---------------------------------------------------------------------------
// h = LN(relu(ctx) + h); ctx f32, h bf16 in/out. One wave per row.
__global__ __launch_bounds__(256) void resln_kernel(
    const float* __restrict__ CTX, u16* Hb,
    const float* __restrict__ gl, const float* __restrict__ bl)
{
  const int t = threadIdx.x;
  const int lane = t & 63;
  const long row = (long)blockIdx.x*4 + (t >> 6);
  const float2 c2 = *(const float2*)&CTX[row*HH + lane*2];
  const u32 hraw = *(const u32*)&Hb[row*HH + lane*2];
  const float h0 = bf2f((u16)(hraw & 0xffff));
  const float h1 = bf2f((u16)(hraw >> 16));
  const float x0 = fmaxf(c2.x, 0.0f) + h0;
  const float x1 = fmaxf(c2.y, 0.0f) + h1;
  float s = x0 + x1, ss = x0*x0 + x1*x1;
  #pragma unroll
  for (int off = 1; off < 64; off <<= 1) {
    s  += __shfl_xor(s,  off);
    ss += __shfl_xor(ss, off);
  }
  const float mean = s * (1.0f/128.0f);
  const float rstd = rsqrtf(ss*(1.0f/128.0f) - mean*mean + 1e-5f);
  const float o0 = (x0 - mean)*rstd*gl[lane*2]   + bl[lane*2];
  const float o1 = (x1 - mean)*rstd*gl[lane*2+1] + bl[lane*2+1];
  *(u32*)&Hb[row*HH + lane*2] = (u32)f2bf(o0) | ((u32)f2bf(o1) << 16);
}

// out[b, col] = max over n of h[b, n, col]; h bf16, out f32
__global__ __launch_bounds__(256) void maxred_kernel(
    const u16* __restrict__ Hb, float* __restrict__ out)
{
  __shared__ float red[256];
  const int b = blockIdx.x;
  const int col = threadIdx.x & 127, half = threadIdx.x >> 7;
  const u16* hp = Hb + ((size_t)b*NN + half*256)*HH + col;
  float m0 = -3.0e38f, m1 = -3.0e38f, m2 = -3.0e38f, m3 = -3.0e38f;
  for (int r = 0; r < 256; r += 4) {
    m0 = fmaxf(m0, bf2f(hp[(r+0)*HH]));
    m1 = fmaxf(m1, bf2f(hp[(r+1)*HH]));
    m2 = fmaxf(m2, bf2f(hp[(r+2)*HH]));
    m3 = fmaxf(m3, bf2f(hp[(r+3)*HH]));
  }
  red[threadIdx.x] = fmaxf(fmaxf(m0, m1), fmaxf(m2, m3));
  __syncthreads();
  if (half == 0) out[(size_t)b*HH + col] = fmaxf(red[col], red[col + 128]);
}

// ---------------------------------------------------------------------------
extern "C" void kernel_launch(void* const* d_in, const int* in_sizes, int n_in,
                              void* d_out, int out_size, void* d_ws, size_t ws_size,
                              hipStream_t stream)
{
  const float* x   = (const float*)d_in[0];
  const int* lens  = (const int*)d_in[1];
  const float* W0  = (const float*)d_in[2];
  const float* b0  = (const float*)d_in[3];
  const float* g0  = (const float*)d_in[4];
  const float* be0 = (const float*)d_in[5];
  const float* W1  = (const float*)d_in[6];
  const float* b1  = (const float*)d_in[7];
  const float* g1  = (const float*)d_in[8];
  const float* be1 = (const float*)d_in[9];
  const float* Wq  = (const float*)d_in[10];
  const float* bq  = (const float*)d_in[11];
  const float* Wk  = (const float*)d_in[12];
  const float* bk  = (const float*)d_in[13];
  const float* Wv  = (const float*)d_in[14];
  const float* bv  = (const float*)d_in[15];
  const float* gl  = (const float*)d_in[16];
  const float* bl  = (const float*)d_in[17];
  float* out = (float*)d_out;

  u16*   h   = (u16*)d_ws;                     // 32MB
  float* ctx = (float*)(h + (size_t)MM*HH);    // 64MB
  u16*   qb  = (u16*)(ctx + (size_t)MM*HH);    // 32MB
  u16*   kb  = qb + (size_t)MM*HH;             // 32MB
  u16*   vb  = kb + (size_t)MM*HH;             // 32MB
  u16*   vT  = vb + (size_t)MM*HH;             // 32MB
  u16*   wt  = vT + (size_t)MM*HH;             // 352KB (11 x 128 x 128 bf16)

  wt_prep<<<11, 256, 0, stream>>>(W0, W1, Wq, Wk, Wv, wt);

  linear_mfma<true ,true ><<<MM/128, 256, 0, stream>>>(x, wt,            b0, g0, be0, h);
  linear_mfma<false,true ><<<MM/128, 256, 0, stream>>>(h, wt + 1*HH*HH,  b1, g1, be1, h);

  for (int d = 0; d < 3; d++) {
    linear_mfma<false,false><<<MM/128, 256, 0, stream>>>(h, wt + (2+3*d)*HH*HH, bq + d*HH, nullptr, nullptr, qb);
    linear_mfma<false,false><<<MM/128, 256, 0, stream>>>(h, wt + (3+3*d)*HH*HH, bk + d*HH, nullptr, nullptr, kb);
    linear_mfma<false,false><<<MM/128, 256, 0, stream>>>(h, wt + (4+3*d)*HH*HH, bv + d*HH, nullptr, nullptr, vb);
    transpose_v_kernel<<<BB*4, 256, 0, stream>>>(vb, vT);
    attn_kernel<<<BB*2*4, 256, 0, stream>>>(qb, kb, vT, lens, ctx);
    resln_kernel<<<MM/4, 256, 0, stream>>>(ctx, h, gl + d*HH, bl + d*HH);
  }
  maxred_kernel<<<BB, 256, 0, stream>>>(h, out);
}

// Round 5
// 619.822 us; speedup vs baseline: 5.0204x; 1.2085x over previous
//
#include <hip/hip_runtime.h>
#include <hip/hip_bf16.h>

#define BB 256
#define NN 512
#define HH 128
#define MM (BB*NN)

typedef unsigned short u16;
typedef unsigned int   u32;
typedef __attribute__((ext_vector_type(8))) short bf16x8;   // 8 bf16 (4 VGPRs)
typedef __attribute__((ext_vector_type(4))) float f32x4;

#define LOG2E  1.4426950408889634f
#define QSCALE (0.125f * LOG2E)       // 1/sqrt(64) folded with log2(e) for exp2
#define NEGB   (-10000.0f * LOG2E)    // mask bias in log2 domain -> exp2 underflows to 0

// byte offset of (row, cbyte) in a [*][64]bf16 (128B-row) LDS tile, XOR-swizzled
__device__ __forceinline__ int kswz(int row, int cbyte) {
  return row*128 + (cbyte ^ ((row & 7) << 4));
}
// same for [*][128]bf16 (256B-row) tiles
__device__ __forceinline__ int wswz(int row, int cbyte) {
  return row*256 + (cbyte ^ ((row & 7) << 4));
}

__device__ __forceinline__ u16 f2bf(float x) {   // f32 -> bf16 RNE
  __hip_bfloat16 h = __float2bfloat16(x);
  return *reinterpret_cast<u16*>(&h);
}
__device__ __forceinline__ float bf2f(u16 x) {
  return __uint_as_float(((u32)x) << 16);
}

// async global->LDS DMA, 16B per lane; LDS dest = wave-uniform base + lane*16.
// Swizzled layouts are achieved by pre-XORing the GLOBAL source address with the
// same involution the LDS reads use (linear dest + inverse-swz source).
__device__ __forceinline__ void gld_lds16(const void* g, void* l) {
  __builtin_amdgcn_global_load_lds(
      (__attribute__((address_space(1))) const unsigned int*)g,
      (__attribute__((address_space(3))) unsigned int*)l, 16, 0, 0);
}

// ---------------------------------------------------------------------------
// Pre-transpose + bf16-convert the 11 weight matrices: wt[i] = W_i^T [c][k]
__global__ __launch_bounds__(256) void wt_prep(
    const float* __restrict__ W0, const float* __restrict__ W1,
    const float* __restrict__ Wq, const float* __restrict__ Wk,
    const float* __restrict__ Wv, u16* __restrict__ wt)
{
  __shared__ u16 tile[128*128];
  const int t = threadIdx.x;
  const int i = blockIdx.x;
  const float* src;
  if (i == 0) src = W0;
  else if (i == 1) src = W1;
  else {
    const int d = (i-2)/3, which = (i-2)%3;
    src = (which==0 ? Wq : which==1 ? Wk : Wv) + d*HH*HH;
  }
  u16* dst = wt + (size_t)i*HH*HH;

  #pragma unroll
  for (int j = 0; j < 8; j++) {
    const int chunk = t + 256*j;
    const int k = chunk >> 4, c8 = (chunk & 15)*8;
    const float4 a = *(const float4*)&src[k*HH + c8];
    const float4 b = *(const float4*)&src[k*HH + c8 + 4];
    union { u16 s[8]; uint4 v; } u;
    u.s[0]=f2bf(a.x); u.s[1]=f2bf(a.y); u.s[2]=f2bf(a.z); u.s[3]=f2bf(a.w);
    u.s[4]=f2bf(b.x); u.s[5]=f2bf(b.y); u.s[6]=f2bf(b.z); u.s[7]=f2bf(b.w);
    *(uint4*)&tile[k*128 + (((chunk & 15) ^ ((k>>3)&7)) << 3)] = u.v;
  }
  __syncthreads();
  #pragma unroll
  for (int j = 0; j < 8; j++) {
    const int chunk = t + 256*j;
    const int c = chunk >> 4, kb8 = (chunk & 15)*8;
    union { u16 s[8]; uint4 v; } u;
    #pragma unroll
    for (int e = 0; e < 8; e++) {
      const int k = kb8 + e;
      u.s[e] = tile[k*128 + ((((c>>3) ^ ((k>>3)&7)) << 3) | (c & 7))];
    }
    *(uint4*)&dst[c*HH + kb8] = u.v;
  }
}

// ---------------------------------------------------------------------------
// Shared body: OUT[M,128](bf16) = LNRELU ? relu(LN(X@W+b)) : X@W+b
// 128 rows/block, 4 waves x 32 rows. WT is bf16 W^T [c][k]. X==OUT safe.
template<bool F32IN, bool LNRELU>
__device__ __forceinline__ void linear_body(
    const void* __restrict__ Xv, const u16* __restrict__ WT,
    const float* __restrict__ bias, const float* __restrict__ gamma,
    const float* __restrict__ beta, u16* __restrict__ OUT,
    u16* wt_s, u16* xs)
{
  const int t = threadIdx.x;
  const int lane = t & 63, w = t >> 6;
  const int l4 = lane >> 4, l15 = lane & 15;
  const long row0 = (long)blockIdx.x * 128;

  // stage W^T via DMA: 32 segs x 1KB (4 rows x 256B), linear dest, pre-swz src
  {
    const int rr = lane >> 4;            // 0..3 row-in-seg
    const int cb = (lane & 15) * 16;     // 0..240
    #pragma unroll
    for (int i = 0; i < 8; i++) {
      const int seg = w*8 + i;
      const int row = seg*4 + rr;
      gld_lds16((const char*)WT + (size_t)row*256 + (cb ^ ((row & 7) << 4)),
                (char*)wt_s + seg*1024);
    }
    if constexpr (!F32IN) {
      const char* xp = (const char*)((const u16*)Xv + row0*HH);
      #pragma unroll
      for (int i = 0; i < 8; i++) {
        const int seg = w*8 + i;
        const int row = seg*4 + rr;
        gld_lds16(xp + (size_t)row*256 + (cb ^ ((row & 7) << 4)),
                  (char*)xs + seg*1024);
      }
    }
  }
  if constexpr (F32IN) {   // f32 input needs cvt: reg-staged swizzled writes
    const float* xp = (const float*)Xv + row0*HH;
    #pragma unroll
    for (int i = 0; i < 8; i++) {
      const int chunk = t + 256*i;
      const int r = chunk >> 4, c8 = (chunk & 15)*8;
      const float4 a = *(const float4*)&xp[r*HH + c8];
      const float4 b = *(const float4*)&xp[r*HH + c8 + 4];
      union { u16 s[8]; uint4 v; } u;
      u.s[0]=f2bf(a.x); u.s[1]=f2bf(a.y); u.s[2]=f2bf(a.z); u.s[3]=f2bf(a.w);
      u.s[4]=f2bf(b.x); u.s[5]=f2bf(b.y); u.s[6]=f2bf(b.z); u.s[7]=f2bf(b.w);
      *(uint4*)((char*)xs + wswz(r, c8*2)) = u.v;
    }
  }
  __syncthreads();   // drains DMA (vmcnt) + LDS writes

  f32x4 acc[2][8];
  #pragma unroll
  for (int m = 0; m < 2; m++)
    #pragma unroll
    for (int n = 0; n < 8; n++)
      { acc[m][n][0]=0.f; acc[m][n][1]=0.f; acc[m][n][2]=0.f; acc[m][n][3]=0.f; }

  #pragma unroll
  for (int ks = 0; ks < 4; ks++) {
    bf16x8 af[2], bf[8];
    #pragma unroll
    for (int m = 0; m < 2; m++)
      af[m] = *(const bf16x8*)((const char*)xs + wswz(w*32 + m*16 + l15, ks*64 + l4*16));
    #pragma unroll
    for (int n = 0; n < 8; n++)
      bf[n] = *(const bf16x8*)((const char*)wt_s + wswz(n*16 + l15, ks*64 + l4*16));
    #pragma unroll
    for (int m = 0; m < 2; m++)
      #pragma unroll
      for (int n = 0; n < 8; n++)
        acc[m][n] = __builtin_amdgcn_mfma_f32_16x16x32_bf16(af[m], bf[n], acc[m][n], 0, 0, 0);
  }

  float bia[8], gam[8], bet[8];
  #pragma unroll
  for (int n = 0; n < 8; n++) {
    bia[n] = bias[n*16 + l15];
    if constexpr (LNRELU) { gam[n] = gamma[n*16 + l15]; bet[n] = beta[n*16 + l15]; }
  }
  #pragma unroll
  for (int m = 0; m < 2; m++) {
    #pragma unroll
    for (int r = 0; r < 4; r++) {
      const long row = row0 + w*32 + m*16 + l4*4 + r;
      float v[8];
      #pragma unroll
      for (int n = 0; n < 8; n++) v[n] = acc[m][n][r] + bia[n];
      if constexpr (LNRELU) {
        float s = 0.f, ss = 0.f;
        #pragma unroll
        for (int n = 0; n < 8; n++) { s += v[n]; ss += v[n]*v[n]; }
        #pragma unroll
        for (int off = 1; off < 16; off <<= 1) {
          s  += __shfl_xor(s,  off);
          ss += __shfl_xor(ss, off);
        }
        const float mean = s * (1.0f/128.0f);
        const float rstd = rsqrtf(ss*(1.0f/128.0f) - mean*mean + 1e-5f);
        #pragma unroll
        for (int n = 0; n < 8; n++)
          v[n] = fmaxf((v[n] - mean)*rstd*gam[n] + bet[n], 0.0f);
      }
      u16* op = OUT + row*HH + l15;
      #pragma unroll
      for (int n = 0; n < 8; n++) op[n*16] = f2bf(v[n]);
    }
  }
}

template<bool F32IN, bool LNRELU>
__global__ __launch_bounds__(256) void linear_mfma(
    const void* __restrict__ Xv, const u16* __restrict__ WT,
    const float* __restrict__ bias, const float* __restrict__ gamma,
    const float* __restrict__ beta, u16* __restrict__ OUT)
{
  __shared__ u16 wt_s[128*128];
  __shared__ u16 xs[128*128];
  linear_body<F32IN, LNRELU>(Xv, WT, bias, gamma, beta, OUT, wt_s, xs);
}

// q/k/v projections in one dispatch; blockIdx.y selects the slice
__global__ __launch_bounds__(256) void qkv_mfma(
    const u16* __restrict__ X, const u16* __restrict__ WTd,
    const float* __restrict__ bq, const float* __restrict__ bk,
    const float* __restrict__ bv,
    u16* __restrict__ qb, u16* __restrict__ kb, u16* __restrict__ vb)
{
  __shared__ u16 wt_s[128*128];
  __shared__ u16 xs[128*128];
  const int y = blockIdx.y;
  const u16* WT = WTd + y*HH*HH;
  const float* bias = (y==0) ? bq : (y==1) ? bk : bv;
  u16* OUT = (y==0) ? qb : (y==1) ? kb : vb;
  linear_body<false, false>(X, WT, bias, nullptr, nullptr, OUT, wt_s, xs);
}

// ---------------------------------------------------------------------------
// v[B*N][128] bf16  ->  vT[(b*2+head)*64 + dh][512] bf16
__global__ __launch_bounds__(256) void transpose_v_kernel(
    const u16* __restrict__ vb, u16* __restrict__ vT)
{
  __shared__ u16 tile[128*128];
  const int t  = threadIdx.x;
  const int b  = blockIdx.x >> 2;
  const int n0 = (blockIdx.x & 3) * 128;

  #pragma unroll
  for (int i = 0; i < 8; i++) {
    const int chunk = t + 256*i;
    const int n = chunk >> 4, cslot = chunk & 15;
    uint4 d = *(const uint4*)(vb + ((size_t)(b*NN + n0 + n))*HH + cslot*8);
    *(uint4*)&tile[n*128 + ((cslot ^ ((n>>3)&7)) << 3)] = d;
  }
  __syncthreads();
  #pragma unroll
  for (int i = 0; i < 8; i++) {
    const int chunk = t + 256*i;
    const int c = chunk >> 4, nb = (chunk & 15) * 8;
    union { u16 s[8]; uint4 v; } u;
    #pragma unroll
    for (int j = 0; j < 8; j++) {
      const int n = nb + j;
      u.s[j] = tile[n*128 + ((((c>>3) ^ ((n>>3)&7)) << 3) | (c & 7))];
    }
    u16* op = vT + (((size_t)(b*2 + (c>>6)))*64 + (c & 63))*NN + n0 + nb;
    *(uint4*)op = u.v;
  }
}

// ---------------------------------------------------------------------------
// Flash attention, bf16 MFMA, fixed-base softmax (no running max: scores are
// bounded << 88 for this model; uniform -10000 bias on invalid q-rows cancels,
// so those rows get bias 0). K/V double-buffered via global_load_lds DMA.
__global__ __launch_bounds__(256) void attn_kernel(
    const u16* __restrict__ Q, const u16* __restrict__ K,
    const u16* __restrict__ VT, const int* __restrict__ lengths,
    u16* __restrict__ CTX)
{
  __shared__ u16 sh_k[2][64*64];   // 2 x 8KB
  __shared__ u16 sh_v[2][64*64];   // 2 x 8KB
  __shared__ u16 sh_pq[128*64];    // Q staging, then per-wave P (16KB)
  const int t    = threadIdx.x;
  const int lane = t & 63;
  const int w    = t >> 6;
  const int bid  = blockIdx.x;
  const int qt   = bid & 3;
  const int head = (bid >> 2) & 1;
  const int b    = bid >> 3;
  const int L    = lengths[b];
  const int q0   = qt * 128;
  const int l4 = lane >> 4, l15 = lane & 15;
  const int rr8 = lane >> 3;          // row-in-seg (8 rows x 128B per 1KB seg)
  const int cb8 = (lane & 7) * 16;

  const char* qbase  = (const char*)(Q + ((size_t)(b*NN + q0))*HH + head*64);
  const char* kbase0 = (const char*)(K + ((size_t)(b*NN))*HH + head*64);
  const char* vbase0 = (const char*)(VT + (((size_t)(b*2 + head))*64)*NN);

  // ---- DMA Q[128][64] (16 segs) + K/V chunk 0 (8 segs each) ----
  #pragma unroll
  for (int i = 0; i < 4; i++) {
    const int seg = w*4 + i;
    const int row = seg*8 + rr8;
    gld_lds16(qbase + (size_t)row*256 + (cb8 ^ ((row&7)<<4)),
              (char*)sh_pq + seg*1024);
  }
  #pragma unroll
  for (int i = 0; i < 2; i++) {
    const int seg = w*2 + i;
    const int row = seg*8 + rr8;
    const int sw = cb8 ^ ((row&7)<<4);
    gld_lds16(kbase0 + (size_t)row*256  + sw, (char*)sh_k[0] + seg*1024);
    gld_lds16(vbase0 + (size_t)row*1024 + sw, (char*)sh_v[0] + seg*1024);
  }
  __syncthreads();   // drains all DMA

  // Q fragments (each wave reads only its own 32 rows)
  bf16x8 qf[2][2];
  #pragma unroll
  for (int m = 0; m < 2; m++)
    #pragma unroll
    for (int ks = 0; ks < 2; ks++)
      qf[m][ks] = *(const bf16x8*)((const char*)sh_pq +
                    kswz(w*32 + m*16 + l15, ks*64 + l4*16));

  u16* p_lds = sh_pq + w*2048;    // this wave's P region [32][64]

  float l_run[2][4];
  f32x4 ctxa[2][4];
  #pragma unroll
  for (int m = 0; m < 2; m++)
    #pragma unroll
    for (int r = 0; r < 4; r++) {
      l_run[m][r] = 0.0f;
      ctxa[m][0][r] = 0.f; ctxa[m][1][r] = 0.f; ctxa[m][2][r] = 0.f; ctxa[m][3][r] = 0.f;
    }

  for (int ch = 0; ch < 8; ch++) {
    const int cur = ch & 1;
    // prefetch next chunk into the other buffer (completes at chunk-end barrier)
    if (ch < 7) {
      const char* kb_ = kbase0 + (size_t)(ch+1)*64*256;
      const char* vb_ = vbase0 + (size_t)(ch+1)*128;
      #pragma unroll
      for (int i = 0; i < 2; i++) {
        const int seg = w*2 + i;
        const int row = seg*8 + rr8;
        const int sw = cb8 ^ ((row&7)<<4);
        gld_lds16(kb_ + (size_t)row*256  + sw, (char*)sh_k[cur^1] + seg*1024);
        gld_lds16(vb_ + (size_t)row*1024 + sw, (char*)sh_v[cur^1] + seg*1024);
      }
    }

    // ---- S = Q K^T ----
    f32x4 acc[2][4];
    #pragma unroll
    for (int m = 0; m < 2; m++)
      #pragma unroll
      for (int n = 0; n < 4; n++)
        { acc[m][n][0]=0.f; acc[m][n][1]=0.f; acc[m][n][2]=0.f; acc[m][n][3]=0.f; }
    #pragma unroll
    for (int ks = 0; ks < 2; ks++) {
      bf16x8 kf[4];
      #pragma unroll
      for (int n = 0; n < 4; n++)
        kf[n] = *(const bf16x8*)((const char*)sh_k[cur] + kswz(n*16 + l15, ks*64 + l4*16));
      #pragma unroll
      for (int m = 0; m < 2; m++)
        #pragma unroll
        for (int n = 0; n < 4; n++)
          acc[m][n] = __builtin_amdgcn_mfma_f32_16x16x32_bf16(
                        qf[m][ks], kf[n], acc[m][n], 0, 0, 0);
    }

    // ---- fixed-base softmax: p = exp2(raw*QSCALE + bias2) ----
    float kb2[4];
    #pragma unroll
    for (int n = 0; n < 4; n++)
      kb2[n] = (ch*64 + n*16 + l15 < L) ? 0.0f : NEGB;

    #pragma unroll
    for (int m = 0; m < 2; m++) {
      #pragma unroll
      for (int r = 0; r < 4; r++) {
        const int  qrow = q0 + w*32 + m*16 + l4*4 + r;
        const bool qv   = qrow < L;       // invalid row: uniform bias cancels -> 0
        const float p0 = exp2f(fmaf(acc[m][0][r], QSCALE, qv ? kb2[0] : 0.0f));
        const float p1 = exp2f(fmaf(acc[m][1][r], QSCALE, qv ? kb2[1] : 0.0f));
        const float p2 = exp2f(fmaf(acc[m][2][r], QSCALE, qv ? kb2[2] : 0.0f));
        const float p3 = exp2f(fmaf(acc[m][3][r], QSCALE, qv ? kb2[3] : 0.0f));
        l_run[m][r] += (p0 + p1) + (p2 + p3);   // per-lane partial row sum
        const int prow = m*16 + l4*4 + r;
        u16* pr = p_lds + prow*64;
        pr[(((0*16 + l15)*2) ^ ((prow&7)<<4)) >> 1] = f2bf(p0);
        pr[(((1*16 + l15)*2) ^ ((prow&7)<<4)) >> 1] = f2bf(p1);
        pr[(((2*16 + l15)*2) ^ ((prow&7)<<4)) >> 1] = f2bf(p2);
        pr[(((3*16 + l15)*2) ^ ((prow&7)<<4)) >> 1] = f2bf(p3);
      }
    }

    // ---- ctx += P V  (A = P rows, B = V^T rows; same-wave LDS is in-order) ----
    #pragma unroll
    for (int ks = 0; ks < 2; ks++) {
      bf16x8 pa[2], vbf[4];
      #pragma unroll
      for (int m = 0; m < 2; m++)
        pa[m] = *(const bf16x8*)((const char*)p_lds + kswz(m*16 + l15, ks*64 + l4*16));
      #pragma unroll
      for (int d = 0; d < 4; d++)
        vbf[d] = *(const bf16x8*)((const char*)sh_v[cur] + kswz(d*16 + l15, ks*64 + l4*16));
      #pragma unroll
      for (int m = 0; m < 2; m++)
        #pragma unroll
        for (int d = 0; d < 4; d++)
          ctxa[m][d] = __builtin_amdgcn_mfma_f32_16x16x32_bf16(
                         pa[m], vbf[d], ctxa[m][d], 0, 0, 0);
    }

    // end of chunk: all waves done with buf cur; next chunk's DMA drained here
    __syncthreads();
  }

  // ---- epilogue: reduce row sums across the 16-lane group, write bf16 ctx ----
  #pragma unroll
  for (int m = 0; m < 2; m++)
    #pragma unroll
    for (int r = 0; r < 4; r++) {
      float lv = l_run[m][r];
      #pragma unroll
      for (int off = 1; off < 16; off <<= 1) lv += __shfl_xor(lv, off);
      const float inv = 1.0f / lv;
      const int qrow = q0 + w*32 + m*16 + l4*4 + r;
      u16* crow = CTX + ((size_t)(b*NN) + qrow)*HH + head*64 + l15;
      crow[0]  = f2bf(ctxa[m][0][r]*inv);
      crow[16] = f2bf(ctxa[m][1][r]*inv);
      crow[32] = f2bf(ctxa[m][2][r]*inv);
      crow[48] = f2bf(ctxa[m][3][r]*inv);
    }
}

// ---------------------------------------------------------------------------
// h = LN(relu(ctx) + h); ctx bf16, h bf16 in/out. One wave per row.
__global__ __launch_bounds__(256) void resln_kernel(
    const u16* __restrict__ CTX, u16* Hb,
    const float* __restrict__ gl, const float* __restrict__ bl)
{
  const int t = threadIdx.x;
  const int lane = t & 63;
  const long row = (long)blockIdx.x*4 + (t >> 6);
  const u32 craw = *(const u32*)&CTX[row*HH + lane*2];
  const u32 hraw = *(const u32*)&Hb[row*HH + lane*2];
  const float c0 = bf2f((u16)(craw & 0xffff)), c1 = bf2f((u16)(craw >> 16));
  const float h0 = bf2f((u16)(hraw & 0xffff)), h1 = bf2f((u16)(hraw >> 16));
  const float x0 = fmaxf(c0, 0.0f) + h0;
  const float x1 = fmaxf(c1, 0.0f) + h1;
  float s = x0 + x1, ss = x0*x0 + x1*x1;
  #pragma unroll
  for (int off = 1; off < 64; off <<= 1) {
    s  += __shfl_xor(s,  off);
    ss += __shfl_xor(ss, off);
  }
  const float mean = s * (1.0f/128.0f);
  const float rstd = rsqrtf(ss*(1.0f/128.0f) - mean*mean + 1e-5f);
  const float o0 = (x0 - mean)*rstd*gl[lane*2]   + bl[lane*2];
  const float o1 = (x1 - mean)*rstd*gl[lane*2+1] + bl[lane*2+1];
  *(u32*)&Hb[row*HH + lane*2] = (u32)f2bf(o0) | ((u32)f2bf(o1) << 16);
}

// out[b, col] = max over n of h[b, n, col]; h bf16, out f32
__global__ __launch_bounds__(256) void maxred_kernel(
    const u16* __restrict__ Hb, float* __restrict__ out)
{
  __shared__ float red[256];
  const int b = blockIdx.x;
  const int col = threadIdx.x & 127, half = threadIdx.x >> 7;
  const u16* hp = Hb + ((size_t)b*NN + half*256)*HH + col;
  float m0 = -3.0e38f, m1 = -3.0e38f, m2 = -3.0e38f, m3 = -3.0e38f;
  for (int r = 0; r < 256; r += 4) {
    m0 = fmaxf(m0, bf2f(hp[(r+0)*HH]));
    m1 = fmaxf(m1, bf2f(hp[(r+1)*HH]));
    m2 = fmaxf(m2, bf2f(hp[(r+2)*HH]));
    m3 = fmaxf(m3, bf2f(hp[(r+3)*HH]));
  }
  red[threadIdx.x] = fmaxf(fmaxf(m0, m1), fmaxf(m2, m3));
  __syncthreads();
  if (half == 0) out[(size_t)b*HH + col] = fmaxf(red[col], red[col + 128]);
}

// ---------------------------------------------------------------------------
extern "C" void kernel_launch(void* const* d_in, const int* in_sizes, int n_in,
                              void* d_out, int out_size, void* d_ws, size_t ws_size,
                              hipStream_t stream)
{
  const float* x   = (const float*)d_in[0];
  const int* lens  = (const int*)d_in[1];
  const float* W0  = (const float*)d_in[2];
  const float* b0  = (const float*)d_in[3];
  const float* g0  = (const float*)d_in[4];
  const float* be0 = (const float*)d_in[5];
  const float* W1  = (const float*)d_in[6];
  const float* b1  = (const float*)d_in[7];
  const float* g1  = (const float*)d_in[8];
  const float* be1 = (const float*)d_in[9];
  const float* Wq  = (const float*)d_in[10];
  const float* bq  = (const float*)d_in[11];
  const float* Wk  = (const float*)d_in[12];
  const float* bk  = (const float*)d_in[13];
  const float* Wv  = (const float*)d_in[14];
  const float* bv  = (const float*)d_in[15];
  const float* gl  = (const float*)d_in[16];
  const float* bl  = (const float*)d_in[17];
  float* out = (float*)d_out;

  u16* h    = (u16*)d_ws;                  // 32MB
  u16* ctxb = h    + (size_t)MM*HH;        // 32MB (bf16 now)
  u16* qb   = ctxb + (size_t)MM*HH;        // 32MB
  u16* kb   = qb   + (size_t)MM*HH;        // 32MB
  u16* vb   = kb   + (size_t)MM*HH;        // 32MB
  u16* vT   = vb   + (size_t)MM*HH;        // 32MB
  u16* wt   = vT   + (size_t)MM*HH;        // 352KB (11 x 128 x 128 bf16)

  wt_prep<<<11, 256, 0, stream>>>(W0, W1, Wq, Wk, Wv, wt);

  linear_mfma<true ,true ><<<MM/128, 256, 0, stream>>>(x, wt,           b0, g0, be0, h);
  linear_mfma<false,true ><<<MM/128, 256, 0, stream>>>(h, wt + 1*HH*HH, b1, g1, be1, h);

  for (int d = 0; d < 3; d++) {
    qkv_mfma<<<dim3(MM/128, 3), 256, 0, stream>>>(
        h, wt + (2+3*d)*HH*HH, bq + d*HH, bk + d*HH, bv + d*HH, qb, kb, vb);
    transpose_v_kernel<<<BB*4, 256, 0, stream>>>(vb, vT);
    attn_kernel<<<BB*2*4, 256, 0, stream>>>(qb, kb, vT, lens, ctxb);
    resln_kernel<<<MM/4, 256, 0, stream>>>(ctxb, h, gl + d*HH, bl + d*HH);
  }
  maxred_kernel<<<BB, 256, 0, stream>>>(h, out);
}

// Round 7
// 578.497 us; speedup vs baseline: 5.3790x; 1.0714x over previous
//
#include <hip/hip_runtime.h>
#include <hip/hip_bf16.h>

#define BB 256
#define NN 512
#define HH 128
#define MM (BB*NN)

typedef unsigned short u16;
typedef unsigned int   u32;
typedef __attribute__((ext_vector_type(8))) short bf16x8;   // 8 bf16 (4 VGPRs)
typedef __attribute__((ext_vector_type(4))) float f32x4;
typedef __attribute__((ext_vector_type(16))) float f32x16;

#define LOG2E  1.4426950408889634f
#define QSCALE (0.125f * LOG2E)       // 1/sqrt(64) folded with log2(e) for exp2
#define NEGB   (-10000.0f * LOG2E)    // mask bias in log2 domain -> exp2 underflows to 0

// byte offset of (row, cbyte) in a [*][64]bf16 (128B-row) LDS tile, XOR-swizzled
__device__ __forceinline__ int kswz(int row, int cbyte) {
  return row*128 + (cbyte ^ ((row & 7) << 4));
}
// same for [*][128]bf16 (256B-row) tiles
__device__ __forceinline__ int wswz(int row, int cbyte) {
  return row*256 + (cbyte ^ ((row & 7) << 4));
}

__device__ __forceinline__ u16 f2bf(float x) {   // f32 -> bf16 RNE
  __hip_bfloat16 h = __float2bfloat16(x);
  return *reinterpret_cast<u16*>(&h);
}
__device__ __forceinline__ float bf2f(u16 x) {
  return __uint_as_float(((u32)x) << 16);
}

// async global->LDS DMA, 16B per lane; LDS dest = wave-uniform base + lane*16.
// Swizzled layouts are achieved by pre-XORing the GLOBAL source address with the
// same involution the LDS reads use (linear dest + inverse-swz source).
__device__ __forceinline__ void gld_lds16(const void* g, void* l) {
  __builtin_amdgcn_global_load_lds(
      (__attribute__((address_space(1))) const unsigned int*)g,
      (__attribute__((address_space(3))) unsigned int*)l, 16, 0, 0);
}

// ---------------------------------------------------------------------------
// Pre-transpose + bf16-convert the 11 weight matrices: wt[i] = W_i^T [c][k]
__global__ __launch_bounds__(256) void wt_prep(
    const float* __restrict__ W0, const float* __restrict__ W1,
    const float* __restrict__ Wq, const float* __restrict__ Wk,
    const float* __restrict__ Wv, u16* __restrict__ wt)
{
  __shared__ u16 tile[128*128];
  const int t = threadIdx.x;
  const int i = blockIdx.x;
  const float* src;
  if (i == 0) src = W0;
  else if (i == 1) src = W1;
  else {
    const int d = (i-2)/3, which = (i-2)%3;
    src = (which==0 ? Wq : which==1 ? Wk : Wv) + d*HH*HH;
  }
  u16* dst = wt + (size_t)i*HH*HH;

  #pragma unroll
  for (int j = 0; j < 8; j++) {
    const int chunk = t + 256*j;
    const int k = chunk >> 4, c8 = (chunk & 15)*8;
    const float4 a = *(const float4*)&src[k*HH + c8];
    const float4 b = *(const float4*)&src[k*HH + c8 + 4];
    union { u16 s[8]; uint4 v; } u;
    u.s[0]=f2bf(a.x); u.s[1]=f2bf(a.y); u.s[2]=f2bf(a.z); u.s[3]=f2bf(a.w);
    u.s[4]=f2bf(b.x); u.s[5]=f2bf(b.y); u.s[6]=f2bf(b.z); u.s[7]=f2bf(b.w);
    *(uint4*)&tile[k*128 + (((chunk & 15) ^ ((k>>3)&7)) << 3)] = u.v;
  }
  __syncthreads();
  #pragma unroll
  for (int j = 0; j < 8; j++) {
    const int chunk = t + 256*j;
    const int c = chunk >> 4, kb8 = (chunk & 15)*8;
    union { u16 s[8]; uint4 v; } u;
    #pragma unroll
    for (int e = 0; e < 8; e++) {
      const int k = kb8 + e;
      u.s[e] = tile[k*128 + ((((c>>3) ^ ((k>>3)&7)) << 3) | (c & 7))];
    }
    *(uint4*)&dst[c*HH + kb8] = u.v;
  }
}

// ---------------------------------------------------------------------------
// Shared body: OUT[M,128](bf16) = LNRELU ? relu(LN(X@W+b)) : X@W+b
// 128 rows/block, 4 waves x 32 rows. WT is bf16 W^T [c][k]. X==OUT safe.
template<bool F32IN, bool LNRELU>
__device__ __forceinline__ void linear_body(
    const void* __restrict__ Xv, const u16* __restrict__ WT,
    const float* __restrict__ bias, const float* __restrict__ gamma,
    const float* __restrict__ beta, u16* __restrict__ OUT,
    u16* wt_s, u16* xs)
{
  const int t = threadIdx.x;
  const int lane = t & 63, w = t >> 6;
  const int l4 = lane >> 4, l15 = lane & 15;
  const long row0 = (long)blockIdx.x * 128;

  // stage W^T via DMA: 32 segs x 1KB (4 rows x 256B), linear dest, pre-swz src
  {
    const int rr = lane >> 4;            // 0..3 row-in-seg
    const int cb = (lane & 15) * 16;     // 0..240
    #pragma unroll
    for (int i = 0; i < 8; i++) {
      const int seg = w*8 + i;
      const int row = seg*4 + rr;
      gld_lds16((const char*)WT + (size_t)row*256 + (cb ^ ((row & 7) << 4)),
                (char*)wt_s + seg*1024);
    }
    if constexpr (!F32IN) {
      const char* xp = (const char*)((const u16*)Xv + row0*HH);
      #pragma unroll
      for (int i = 0; i < 8; i++) {
        const int seg = w*8 + i;
        const int row = seg*4 + rr;
        gld_lds16(xp + (size_t)row*256 + (cb ^ ((row & 7) << 4)),
                  (char*)xs + seg*1024);
      }
    }
  }
  if constexpr (F32IN) {   // f32 input needs cvt: reg-staged swizzled writes
    const float* xp = (const float*)Xv + row0*HH;
    #pragma unroll
    for (int i = 0; i < 8; i++) {
      const int chunk = t + 256*i;
      const int r = chunk >> 4, c8 = (chunk & 15)*8;
      const float4 a = *(const float4*)&xp[r*HH + c8];
      const float4 b = *(const float4*)&xp[r*HH + c8 + 4];
      union { u16 s[8]; uint4 v; } u;
      u.s[0]=f2bf(a.x); u.s[1]=f2bf(a.y); u.s[2]=f2bf(a.z); u.s[3]=f2bf(a.w);
      u.s[4]=f2bf(b.x); u.s[5]=f2bf(b.y); u.s[6]=f2bf(b.z); u.s[7]=f2bf(b.w);
      *(uint4*)((char*)xs + wswz(r, c8*2)) = u.v;
    }
  }
  __syncthreads();   // drains DMA (vmcnt) + LDS writes

  f32x4 acc[2][8];
  #pragma unroll
  for (int m = 0; m < 2; m++)
    #pragma unroll
    for (int n = 0; n < 8; n++)
      { acc[m][n][0]=0.f; acc[m][n][1]=0.f; acc[m][n][2]=0.f; acc[m][n][3]=0.f; }

  #pragma unroll
  for (int ks = 0; ks < 4; ks++) {
    bf16x8 af[2], bf[8];
    #pragma unroll
    for (int m = 0; m < 2; m++)
      af[m] = *(const bf16x8*)((const char*)xs + wswz(w*32 + m*16 + l15, ks*64 + l4*16));
    #pragma unroll
    for (int n = 0; n < 8; n++)
      bf[n] = *(const bf16x8*)((const char*)wt_s + wswz(n*16 + l15, ks*64 + l4*16));
    #pragma unroll
    for (int m = 0; m < 2; m++)
      #pragma unroll
      for (int n = 0; n < 8; n++)
        acc[m][n] = __builtin_amdgcn_mfma_f32_16x16x32_bf16(af[m], bf[n], acc[m][n], 0, 0, 0);
  }

  float bia[8], gam[8], bet[8];
  #pragma unroll
  for (int n = 0; n < 8; n++) {
    bia[n] = bias[n*16 + l15];
    if constexpr (LNRELU) { gam[n] = gamma[n*16 + l15]; bet[n] = beta[n*16 + l15]; }
  }
  #pragma unroll
  for (int m = 0; m < 2; m++) {
    #pragma unroll
    for (int r = 0; r < 4; r++) {
      const long row = row0 + w*32 + m*16 + l4*4 + r;
      float v[8];
      #pragma unroll
      for (int n = 0; n < 8; n++) v[n] = acc[m][n][r] + bia[n];
      if constexpr (LNRELU) {
        float s = 0.f, ss = 0.f;
        #pragma unroll
        for (int n = 0; n < 8; n++) { s += v[n]; ss += v[n]*v[n]; }
        #pragma unroll
        for (int off = 1; off < 16; off <<= 1) {
          s  += __shfl_xor(s,  off);
          ss += __shfl_xor(ss, off);
        }
        const float mean = s * (1.0f/128.0f);
        const float rstd = rsqrtf(ss*(1.0f/128.0f) - mean*mean + 1e-5f);
        #pragma unroll
        for (int n = 0; n < 8; n++)
          v[n] = fmaxf((v[n] - mean)*rstd*gam[n] + bet[n], 0.0f);
      }
      u16* op = OUT + row*HH + l15;
      #pragma unroll
      for (int n = 0; n < 8; n++) op[n*16] = f2bf(v[n]);
    }
  }
}

template<bool F32IN, bool LNRELU>
__global__ __launch_bounds__(256) void linear_mfma(
    const void* __restrict__ Xv, const u16* __restrict__ WT,
    const float* __restrict__ bias, const float* __restrict__ gamma,
    const float* __restrict__ beta, u16* __restrict__ OUT)
{
  __shared__ u16 wt_s[128*128];
  __shared__ u16 xs[128*128];
  linear_body<F32IN, LNRELU>(Xv, WT, bias, gamma, beta, OUT, wt_s, xs);
}

// q/k/v projections in one dispatch; blockIdx.y selects the slice
__global__ __launch_bounds__(256) void qkv_mfma(
    const u16* __restrict__ X, const u16* __restrict__ WTd,
    const float* __restrict__ bq, const float* __restrict__ bk,
    const float* __restrict__ bv,
    u16* __restrict__ qb, u16* __restrict__ kb, u16* __restrict__ vb)
{
  __shared__ u16 wt_s[128*128];
  __shared__ u16 xs[128*128];
  const int y = blockIdx.y;
  const u16* WT = WTd + y*HH*HH;
  const float* bias = (y==0) ? bq : (y==1) ? bk : bv;
  u16* OUT = (y==0) ? qb : (y==1) ? kb : vb;
  linear_body<false, false>(X, WT, bias, nullptr, nullptr, OUT, wt_s, xs);
}

// ---------------------------------------------------------------------------
// v[B*N][128] bf16  ->  vT[(b*2+head)*64 + dh][512] bf16
__global__ __launch_bounds__(256) void transpose_v_kernel(
    const u16* __restrict__ vb, u16* __restrict__ vT)
{
  __shared__ u16 tile[128*128];
  const int t  = threadIdx.x;
  const int b  = blockIdx.x >> 2;
  const int n0 = (blockIdx.x & 3) * 128;

  #pragma unroll
  for (int i = 0; i < 8; i++) {
    const int chunk = t + 256*i;
    const int n = chunk >> 4, cslot = chunk & 15;
    uint4 d = *(const uint4*)(vb + ((size_t)(b*NN + n0 + n))*HH + cslot*8);
    *(uint4*)&tile[n*128 + ((cslot ^ ((n>>3)&7)) << 3)] = d;
  }
  __syncthreads();
  #pragma unroll
  for (int i = 0; i < 8; i++) {
    const int chunk = t + 256*i;
    const int c = chunk >> 4, nb = (chunk & 15) * 8;
    union { u16 s[8]; uint4 v; } u;
    #pragma unroll
    for (int j = 0; j < 8; j++) {
      const int n = nb + j;
      u.s[j] = tile[n*128 + ((((c>>3) ^ ((n>>3)&7)) << 3) | (c & 7))];
    }
    u16* op = vT + (((size_t)(b*2 + (c>>6)))*64 + (c & 63))*NN + n0 + nb;
    *(uint4*)op = u.v;
  }
}

// ---------------------------------------------------------------------------
// Flash attention, swapped 32x32 MFMA, P kept in registers.
// Block = (b, head, 128-row q-tile), 4 waves x 32 q-rows; lane owns q = lane&31.
// S^T = mfma(K, Q): C layout col=lane&31=q, row(reg,hi)=(reg&3)+8*(reg>>2)+4*hi = key.
// PV: ctx^T = mfma(A=V^T, B=P^T); B-frag k-pattern = 8*hi + j, built from packed
// bf16 pairs with one shfl_xor(32) per word (cross-half exchange).
__global__ __launch_bounds__(256) void attn_kernel(
    const u16* __restrict__ Q, const u16* __restrict__ K,
    const u16* __restrict__ VT, const int* __restrict__ lengths,
    u16* __restrict__ CTX)
{
  __shared__ u16 sh_q[128*64];     // 16KB
  __shared__ u16 sh_k[2][64*64];   // 16KB
  __shared__ u16 sh_v[2][64*64];   // 16KB
  const int t    = threadIdx.x;
  const int lane = t & 63;
  const int w    = t >> 6;
  const int bid  = blockIdx.x;
  const int qt   = bid & 3;
  const int head = (bid >> 2) & 1;
  const int b    = bid >> 3;
  const int L    = lengths[b];
  const int q0   = qt * 128;
  const int l31  = lane & 31;
  const int hi   = lane >> 5;
  const int rr8  = lane >> 3;          // DMA: row-in-seg (8 rows x 128B per 1KB seg)
  const int cb8  = (lane & 7) * 16;

  const char* qbase  = (const char*)(Q + ((size_t)(b*NN + q0))*HH + head*64);
  const char* kbase0 = (const char*)(K + ((size_t)(b*NN))*HH + head*64);
  const char* vbase0 = (const char*)(VT + (((size_t)(b*2 + head))*64)*NN);

  // ---- DMA Q[128][64] (16 segs) + K/V chunk 0 (8 segs each) ----
  #pragma unroll
  for (int i = 0; i < 4; i++) {
    const int seg = w*4 + i;
    const int row = seg*8 + rr8;
    gld_lds16(qbase + (size_t)row*256 + (cb8 ^ ((row&7)<<4)),
              (char*)sh_q + seg*1024);
  }
  #pragma unroll
  for (int i = 0; i < 2; i++) {
    const int seg = w*2 + i;
    const int row = seg*8 + rr8;
    const int sw = cb8 ^ ((row&7)<<4);
    gld_lds16(kbase0 + (size_t)row*256  + sw, (char*)sh_k[0] + seg*1024);
    gld_lds16(vbase0 + (size_t)row*1024 + sw, (char*)sh_v[0] + seg*1024);
  }
  __syncthreads();   // drains all DMA

  // Q fragments (B-operand): lane holds Q[q=l31][dh=16*st + 8*hi + j]
  bf16x8 qf[4];
  #pragma unroll
  for (int st = 0; st < 4; st++)
    qf[st] = *(const bf16x8*)((const char*)sh_q + kswz(w*32 + l31, st*32 + hi*16));

  f32x16 cacc[2];   // ctx^T accumulators (dh blocks 0-31, 32-63)
  #pragma unroll
  for (int r = 0; r < 16; r++) { cacc[0][r] = 0.f; cacc[1][r] = 0.f; }
  float l_run = 0.0f;

  const bool q_allv   = (q0 + w*32 + 31) < L;   // wave-uniform
  const bool q_allinv = (q0 + w*32) >= L;       // wave-uniform
  const bool qv       = (q0 + w*32 + l31) < L;  // per-lane
  const int  nch      = (q0 + 127 < L) ? ((L + 63) >> 6) : 8;  // block-uniform

  for (int ch = 0; ch < nch; ch++) {
    const int cur = ch & 1;
    // prefetch next chunk into the other buffer (drains at chunk-end barrier)
    if (ch + 1 < nch) {
      const char* kb_ = kbase0 + (size_t)(ch+1)*64*256;
      const char* vb_ = vbase0 + (size_t)(ch+1)*128;
      #pragma unroll
      for (int i = 0; i < 2; i++) {
        const int seg = w*2 + i;
        const int row = seg*8 + rr8;
        const int sw = cb8 ^ ((row&7)<<4);
        gld_lds16(kb_ + (size_t)row*256  + sw, (char*)sh_k[cur^1] + seg*1024);
        gld_lds16(vb_ + (size_t)row*1024 + sw, (char*)sh_v[cur^1] + seg*1024);
      }
    }

    // fully-valid wave + fully-invalid chunk: P == 0, skip all compute
    const bool skip = q_allv && (ch*64 >= L);
    if (!skip) {
      // ---- S^T = K Q^T ----
      f32x16 sacc[2];
      #pragma unroll
      for (int r = 0; r < 16; r++) { sacc[0][r] = 0.f; sacc[1][r] = 0.f; }
      #pragma unroll
      for (int st = 0; st < 4; st++) {
        const bf16x8 kf0 = *(const bf16x8*)((const char*)sh_k[cur] + kswz(l31,      st*32 + hi*16));
        const bf16x8 kf1 = *(const bf16x8*)((const char*)sh_k[cur] + kswz(32 + l31, st*32 + hi*16));
        sacc[0] = __builtin_amdgcn_mfma_f32_32x32x16_bf16(kf0, qf[st], sacc[0], 0, 0, 0);
        sacc[1] = __builtin_amdgcn_mfma_f32_32x32x16_bf16(kf1, qf[st], sacc[1], 0, 0, 0);
      }

      // ---- softmax (lane-local rows) + pack P to bf16 words ----
      // pw[kb][m*2+e] packs keys {8m+4hi+2e, +1} of block kb, row q=l31
      const bool fast = (ch*64 + 63 < L) || q_allinv;
      u32 pw[2][8];
      #pragma unroll
      for (int kb2 = 0; kb2 < 2; kb2++) {
        float p[16];
        float psum = 0.f;
        if (fast) {
          #pragma unroll
          for (int r = 0; r < 16; r++) {
            p[r] = exp2f(sacc[kb2][r] * QSCALE);
            psum += p[r];
          }
        } else {
          #pragma unroll
          for (int r = 0; r < 16; r++) {
            const int key = ch*64 + kb2*32 + (r&3) + 8*(r>>2) + 4*hi;
            const float bias = (qv && key >= L) ? NEGB : 0.0f;
            p[r] = exp2f(fmaf(sacc[kb2][r], QSCALE, bias));
            psum += p[r];
          }
        }
        l_run += psum;
        #pragma unroll
        for (int mm = 0; mm < 4; mm++)
          #pragma unroll
          for (int e = 0; e < 2; e++)
            pw[kb2][mm*2+e] = (u32)f2bf(p[4*mm+2*e]) | ((u32)f2bf(p[4*mm+2*e+1]) << 16);
      }

      // ---- PV: ctx^T += V^T P^T ----
      #pragma unroll
      for (int kb2 = 0; kb2 < 2; kb2++) {
        #pragma unroll
        for (int st = 0; st < 2; st++) {
          // frag needs half0's w[2st+hi][e] then half1's w[2st+hi][e];
          // exchange w[2st+1-hi][e] both ways via shfl_xor(32).
          const u32 w00 = pw[kb2][(2*st+0)*2+0], w01 = pw[kb2][(2*st+0)*2+1];
          const u32 w10 = pw[kb2][(2*st+1)*2+0], w11 = pw[kb2][(2*st+1)*2+1];
          const u32 own0 = hi ? w10 : w00;
          const u32 own1 = hi ? w11 : w01;
          const u32 snd0 = hi ? w00 : w10;
          const u32 snd1 = hi ? w01 : w11;
          const u32 rcv0 = (u32)__shfl_xor((int)snd0, 32);
          const u32 rcv1 = (u32)__shfl_xor((int)snd1, 32);
          union { u32 u[4]; bf16x8 v; } pb;
          pb.u[0] = hi ? rcv0 : own0;
          pb.u[1] = hi ? rcv1 : own1;
          pb.u[2] = hi ? own0 : rcv0;
          pb.u[3] = hi ? own1 : rcv1;
          #pragma unroll
          for (int db = 0; db < 2; db++) {
            const bf16x8 vf = *(const bf16x8*)((const char*)sh_v[cur] +
                                kswz(db*32 + l31, kb2*64 + st*32 + hi*16));
            cacc[db] = __builtin_amdgcn_mfma_f32_32x32x16_bf16(vf, pb.v, cacc[db], 0, 0, 0);
          }
        }
      }
    }

    __syncthreads();   // buf cur consumed everywhere; next chunk's DMA drained
  }

  // ---- epilogue: full row-sum via one cross-half shuffle; lane-local write ----
  const float l_full = l_run + __shfl_xor(l_run, 32);
  const float inv = 1.0f / l_full;
  const int qrow = q0 + w*32 + l31;
  u16* crow = CTX + ((size_t)(b*NN) + qrow)*HH + head*64;
  #pragma unroll
  for (int db = 0; db < 2; db++)
    #pragma unroll
    for (int mm = 0; mm < 4; mm++) {
      const int dh0 = db*32 + mm*8 + hi*4;   // dh = dh0 + e, e=0..3
      uint2 o;
      o.x = (u32)f2bf(cacc[db][4*mm+0]*inv) | ((u32)f2bf(cacc[db][4*mm+1]*inv) << 16);
      o.y = (u32)f2bf(cacc[db][4*mm+2]*inv) | ((u32)f2bf(cacc[db][4*mm+3]*inv) << 16);
      *(uint2*)(crow + dh0) = o;
    }
}

// ---------------------------------------------------------------------------
// h = LN(relu(ctx) + h); ctx bf16, h bf16 in/out. One wave per row.
__global__ __launch_bounds__(256) void resln_kernel(
    const u16* __restrict__ CTX, u16* Hb,
    const float* __restrict__ gl, const float* __restrict__ bl)
{
  const int t = threadIdx.x;
  const int lane = t & 63;
  const long row = (long)blockIdx.x*4 + (t >> 6);
  const u32 craw = *(const u32*)&CTX[row*HH + lane*2];
  const u32 hraw = *(const u32*)&Hb[row*HH + lane*2];
  const float c0 = bf2f((u16)(craw & 0xffff)), c1 = bf2f((u16)(craw >> 16));
  const float h0 = bf2f((u16)(hraw & 0xffff)), h1 = bf2f((u16)(hraw >> 16));
  const float x0 = fmaxf(c0, 0.0f) + h0;
  const float x1 = fmaxf(c1, 0.0f) + h1;
  float s = x0 + x1, ss = x0*x0 + x1*x1;
  #pragma unroll
  for (int off = 1; off < 64; off <<= 1) {
    s  += __shfl_xor(s,  off);
    ss += __shfl_xor(ss, off);
  }
  const float mean = s * (1.0f/128.0f);
  const float rstd = rsqrtf(ss*(1.0f/128.0f) - mean*mean + 1e-5f);
  const float o0 = (x0 - mean)*rstd*gl[lane*2]   + bl[lane*2];
  const float o1 = (x1 - mean)*rstd*gl[lane*2+1] + bl[lane*2+1];
  *(u32*)&Hb[row*HH + lane*2] = (u32)f2bf(o0) | ((u32)f2bf(o1) << 16);
}

// out[b, col] = max over n of h[b, n, col]; h bf16, out f32
__global__ __launch_bounds__(256) void maxred_kernel(
    const u16* __restrict__ Hb, float* __restrict__ out)
{
  __shared__ float red[256];
  const int b = blockIdx.x;
  const int col = threadIdx.x & 127, half = threadIdx.x >> 7;
  const u16* hp = Hb + ((size_t)b*NN + half*256)*HH + col;
  float m0 = -3.0e38f, m1 = -3.0e38f, m2 = -3.0e38f, m3 = -3.0e38f;
  for (int r = 0; r < 256; r += 4) {
    m0 = fmaxf(m0, bf2f(hp[(r+0)*HH]));
    m1 = fmaxf(m1, bf2f(hp[(r+1)*HH]));
    m2 = fmaxf(m2, bf2f(hp[(r+2)*HH]));
    m3 = fmaxf(m3, bf2f(hp[(r+3)*HH]));
  }
  red[threadIdx.x] = fmaxf(fmaxf(m0, m1), fmaxf(m2, m3));
  __syncthreads();
  if (half == 0) out[(size_t)b*HH + col] = fmaxf(red[col], red[col + 128]);
}

// ---------------------------------------------------------------------------
extern "C" void kernel_launch(void* const* d_in, const int* in_sizes, int n_in,
                              void* d_out, int out_size, void* d_ws, size_t ws_size,
                              hipStream_t stream)
{
  const float* x   = (const float*)d_in[0];
  const int* lens  = (const int*)d_in[1];
  const float* W0  = (const float*)d_in[2];
  const float* b0  = (const float*)d_in[3];
  const float* g0  = (const float*)d_in[4];
  const float* be0 = (const float*)d_in[5];
  const float* W1  = (const float*)d_in[6];
  const float* b1  = (const float*)d_in[7];
  const float* g1  = (const float*)d_in[8];
  const float* be1 = (const float*)d_in[9];
  const float* Wq  = (const float*)d_in[10];
  const float* bq  = (const float*)d_in[11];
  const float* Wk  = (const float*)d_in[12];
  const float* bk  = (const float*)d_in[13];
  const float* Wv  = (const float*)d_in[14];
  const float* bv  = (const float*)d_in[15];
  const float* gl  = (const float*)d_in[16];
  const float* bl  = (const float*)d_in[17];
  float* out = (float*)d_out;

  u16* h    = (u16*)d_ws;                  // 32MB
  u16* ctxb = h    + (size_t)MM*HH;        // 32MB
  u16* qb   = ctxb + (size_t)MM*HH;        // 32MB
  u16* kb   = qb   + (size_t)MM*HH;        // 32MB
  u16* vb   = kb   + (size_t)MM*HH;        // 32MB
  u16* vT   = vb   + (size_t)MM*HH;        // 32MB
  u16* wt   = vT   + (size_t)MM*HH;        // 352KB (11 x 128 x 128 bf16)

  wt_prep<<<11, 256, 0, stream>>>(W0, W1, Wq, Wk, Wv, wt);

  linear_mfma<true ,true ><<<MM/128, 256, 0, stream>>>(x, wt,           b0, g0, be0, h);
  linear_mfma<false,true ><<<MM/128, 256, 0, stream>>>(h, wt + 1*HH*HH, b1, g1, be1, h);

  for (int d = 0; d < 3; d++) {
    qkv_mfma<<<dim3(MM/128, 3), 256, 0, stream>>>(
        h, wt + (2+3*d)*HH*HH, bq + d*HH, bk + d*HH, bv + d*HH, qb, kb, vb);
    transpose_v_kernel<<<BB*4, 256, 0, stream>>>(vb, vT);
    attn_kernel<<<BB*2*4, 256, 0, stream>>>(qb, kb, vT, lens, ctxb);
    resln_kernel<<<MM/4, 256, 0, stream>>>(ctxb, h, gl + d*HH, bl + d*HH);
  }
  maxred_kernel<<<BB, 256, 0, stream>>>(h, out);
}